// Round 5
// baseline (387.778 us; speedup 1.0000x reference)
//
#include <hip/hip_runtime.h>
#include <hip/hip_bf16.h>

#define NB 128      // batch
#define NT 128      // Tm1
#define ND 128      // input size (drivers)
#define NH 64       // hidden
#define NTH 1024    // threads per block
#define ESTR 144    // Ebt row stride (ushorts)

__device__ __forceinline__ float fexp2(float x) { return __builtin_amdgcn_exp2f(x); }
__device__ __forceinline__ float frcp (float x) { return __builtin_amdgcn_rcpf(x); }

// DPP-based partial-sum add: v += lane-permuted(v)
template<int CTRL>
__device__ __forceinline__ float dppadd(float v) {
  return v + __int_as_float(__builtin_amdgcn_update_dpp(
      0, __float_as_int(v), CTRL, 0xF, 0xF, true));
}
// sum over each 16-lane group
__device__ __forceinline__ float sum16(float v) {
  v = dppadd<0xB1>(v);   // quad_perm [1,0,3,2]
  v = dppadd<0x4E>(v);   // quad_perm [2,3,0,1]
  v = dppadd<0x141>(v);  // row_half_mirror
  v = dppadd<0x140>(v);  // row_mirror
  return v;
}

// f32 -> bf16 bits, round-to-nearest-even
__device__ __forceinline__ unsigned short f2bf(float f) {
  unsigned u = __float_as_uint(f);
  u += 0x7fffu + ((u >> 16) & 1u);
  return (unsigned short)(u >> 16);
}

// amdgpu_waves_per_eu(4,4): pin the register allocator's occupancy TARGET to
// 4 waves/EU (the structural max: 138KB LDS -> 1 block/CU -> 16 waves/CU).
// launch_bounds(,4) alone was a no-op (r4: identical binary) because it only
// sets the min; the allocator still targeted 8 waves/EU = 64-VGPR bin and
// spilled the ~85 persistent weight values. Budget here: 512/4 = 128 VGPR.
__global__ __launch_bounds__(NTH)
__attribute__((amdgpu_waves_per_eu(4, 4)))
void darnn_enc(
    const float* __restrict__ x,     // [B][T1][D]
    const float* __restrict__ Wehs,  // [T1][2H]
    const float* __restrict__ behs,  // [T1]
    const float* __restrict__ Ue,    // [T1][T1]
    const float* __restrict__ Ueb,   // [T1]
    const float* __restrict__ vew,   // [T1]
    const float* __restrict__ Wih,   // [4H][D]
    const float* __restrict__ Whh,   // [4H][H]
    const float* __restrict__ bih,   // [256]
    const float* __restrict__ bhh,   // [256]
    float* __restrict__ out)
{
  constexpr float C2  = 2.88539008177792681f;  // 2*log2(e)
  constexpr float L2E = 1.44269504088896340f;  // log2(e)

  __shared__ __align__(16) float          xh[NT][ND];     // 64K: x, overwritten by x_hat
  __shared__ __align__(16) unsigned short Ebt[ND][ESTR];  // 36.9K: E bf16 (prologue)
  __shared__ __align__(16) float          hbuf[NT][NH];   // 32K: h outputs (prologue: UeTc)
  __shared__ __align__(16) float          hq[2][16][6];   // h chunks of 4, padded, dbuf
  __shared__ __align__(16) float          cq[2][16][6];   // c chunks of 4, padded, dbuf
  __shared__ __align__(16) float          wvp[16][12];    // w_s = exp(2*we) chunked+padded
  __shared__ __align__(16) float          xpad[16][10];   // ex = e*x chunks of 8, padded
  __shared__ __align__(16) float          part[16];       // per-wave sum of e

  const int b    = blockIdx.x;
  const int tid  = threadIdx.x;
  const int lane = tid & 63;
  const int wid  = tid >> 6;
  const float* xb = x + b * (NT * ND);

  // ---------------- stage x into LDS ---------------------------------------
#pragma unroll
  for (int i = 0; i < 4; ++i) {
    const int f = i * 1024 + tid;
    const int t = f >> 5, c = (f & 31) << 2;
    *reinterpret_cast<float4*>(&xh[t][c]) =
        *reinterpret_cast<const float4*>(xb + t * ND + c);
  }
  float (*UeTc)[33] = reinterpret_cast<float(*)[33]>(&hbuf[0][0]);
  __syncthreads();

  // ---------------- Prologue: E[d][s] = exp(2*(x_perm @ Ue^T + Ueb)) --------
  {
    const int dq = tid & 31;
    const int sg = tid >> 5;
    float acc[16];
#pragma unroll
    for (int i = 0; i < 16; ++i) acc[i] = 0.f;
    for (int c = 0; c < 4; ++c) {
      {
        const int ss = 32 * c + sg;
        const int t4 = dq * 4;
        const float4 u4 = *reinterpret_cast<const float4*>(Ue + ss * NT + t4);
        UeTc[t4 + 0][sg] = u4.x;
        UeTc[t4 + 1][sg] = u4.y;
        UeTc[t4 + 2][sg] = u4.z;
        UeTc[t4 + 3][sg] = u4.w;
      }
      __syncthreads();
#pragma unroll 4
      for (int t = 0; t < NT; ++t) {
        const float4 xv = *reinterpret_cast<const float4*>(&xh[t][4 * dq]);
        const float u = UeTc[t][sg];
        acc[4*c+0] = fmaf(xv.x, u, acc[4*c+0]);
        acc[4*c+1] = fmaf(xv.y, u, acc[4*c+1]);
        acc[4*c+2] = fmaf(xv.z, u, acc[4*c+2]);
        acc[4*c+3] = fmaf(xv.w, u, acc[4*c+3]);
      }
      __syncthreads();
    }
#pragma unroll
    for (int c = 0; c < 4; ++c) {
      const int ss = sg + 32 * c;
      const float ub = Ueb[ss];
#pragma unroll
      for (int di = 0; di < 4; ++di) {
        const float e = fexp2(C2 * (acc[4*c+di] + ub));
        Ebt[4*dq + di][ss] = f2bf(e);
      }
    }
  }
  __syncthreads();   // Ebt complete before register loads

  // zero h/c state (both parities)
  if (tid < 192) (&hq[0][0][0])[tid] = 0.f;
  if (tid < 192) (&cq[0][0][0])[tid] = 0.f;

  // ---------------- persistent per-thread registers -------------------------
  // phase A: 8 threads per s
  const int s_a = tid >> 3, r_a = tid & 7;
  float wehs_r[16];
#pragma unroll
  for (int i = 0; i < 4; ++i) {
    const float4 v4 = *reinterpret_cast<const float4*>(Wehs + s_a * 128 + r_a * 16 + 4 * i);
    wehs_r[4*i+0] = v4.x; wehs_r[4*i+1] = v4.y; wehs_r[4*i+2] = v4.z; wehs_r[4*i+3] = v4.w;
  }
  const float behs_r = behs[s_a];

  // phase B: lane = s_l + 16*dp; d0 = 8*wid + 2*dp
  const int s_l = lane & 15;
  const int dp  = lane >> 4;
  const int d0  = 8 * wid + 2 * dp;
  float m2vw[8];
  {
    const float4 va = *reinterpret_cast<const float4*>(vew + 8 * s_l);
    const float4 vb = *reinterpret_cast<const float4*>(vew + 8 * s_l + 4);
    m2vw[0] = -2.f * va.x; m2vw[1] = -2.f * va.y; m2vw[2] = -2.f * va.z; m2vw[3] = -2.f * va.w;
    m2vw[4] = -2.f * vb.x; m2vw[5] = -2.f * vb.y; m2vw[6] = -2.f * vb.z; m2vw[7] = -2.f * vb.w;
  }
  // E fragments into registers (time-invariant)
  int er[8];
  {
    const int4 ea = *reinterpret_cast<const int4*>(&Ebt[d0][8 * s_l]);
    const int4 eb = *reinterpret_cast<const int4*>(&Ebt[d0 + 1][8 * s_l]);
    er[0] = ea.x; er[1] = ea.y; er[2] = ea.z; er[3] = ea.w;
    er[4] = eb.x; er[5] = eb.y; er[6] = eb.z; er[7] = eb.w;
  }

  // phase D+E: lane = 16*kk + cD; unit kD = 4*wid + kk; all 4 gates per lane
  const int kk = lane >> 4, cD = lane & 15;
  const int kD = 4 * wid + kk;
  float wxr[4][8], whr[4][4], b4[4];
#pragma unroll
  for (int g = 0; g < 4; ++g) {
    const int j = 64 * g + kD;
    const float4 u0 = *reinterpret_cast<const float4*>(Wih + j * 128 + 8 * cD);
    const float4 u1 = *reinterpret_cast<const float4*>(Wih + j * 128 + 8 * cD + 4);
    wxr[g][0] = u0.x; wxr[g][1] = u0.y; wxr[g][2] = u0.z; wxr[g][3] = u0.w;
    wxr[g][4] = u1.x; wxr[g][5] = u1.y; wxr[g][6] = u1.z; wxr[g][7] = u1.w;
    const float4 u2 = *reinterpret_cast<const float4*>(Whh + j * 64 + 4 * cD);
    whr[g][0] = u2.x; whr[g][1] = u2.y; whr[g][2] = u2.z; whr[g][3] = u2.w;
    b4[g] = bih[j] + bhh[j];
  }

  __syncthreads();

  // ---------------- main recurrence: 3 barriers/step, no global mem ---------
  int p = 0;
  for (int t = 0; t < NT; ++t) {
    // ---- A: we[s] = behs[s] + hc . Wehs[s,:];  w_s = exp(2*we)
    {
      const float* src = (r_a < 4) ? &hq[p][4 * (r_a & 3)][0] : &cq[p][4 * (r_a & 3)][0];
      float a0 = 0.f;
#pragma unroll
      for (int i = 0; i < 4; ++i) {
        const float4 h4 = *reinterpret_cast<const float4*>(src + 6 * i);
        a0 = fmaf(h4.x, wehs_r[4*i+0], a0);
        a0 = fmaf(h4.y, wehs_r[4*i+1], a0);
        a0 = fmaf(h4.z, wehs_r[4*i+2], a0);
        a0 = fmaf(h4.w, wehs_r[4*i+3], a0);
      }
      a0 = dppadd<0xB1>(a0);
      a0 = dppadd<0x4E>(a0);
      a0 = dppadd<0x141>(a0);
      if (r_a == 0) wvp[s_a >> 3][s_a & 7] = fexp2(C2 * (a0 + behs_r));
    }
    __syncthreads();

    // ---- B': v[d] -> e[d] = exp(v); writers stage ex = e*x; wave partial Σe
    {
      const float4 wa = *reinterpret_cast<const float4*>(&wvp[s_l][0]);
      const float4 wb = *reinterpret_cast<const float4*>(&wvp[s_l][4]);
      const float wj0 = wa.x, wj1 = wa.y, wj2 = wa.z, wj3 = wa.w;
      const float wj4 = wb.x, wj5 = wb.y, wj6 = wb.z, wj7 = wb.w;
      float a0 = 0.f, a1 = 0.f;
      unsigned u;
      u = (unsigned)er[0];
      a0 = fmaf(m2vw[0], frcp(fmaf(wj0, __uint_as_float(u << 16),         1.f)), a0);
      a0 = fmaf(m2vw[1], frcp(fmaf(wj1, __uint_as_float(u & 0xffff0000u), 1.f)), a0);
      u = (unsigned)er[1];
      a0 = fmaf(m2vw[2], frcp(fmaf(wj2, __uint_as_float(u << 16),         1.f)), a0);
      a0 = fmaf(m2vw[3], frcp(fmaf(wj3, __uint_as_float(u & 0xffff0000u), 1.f)), a0);
      u = (unsigned)er[2];
      a0 = fmaf(m2vw[4], frcp(fmaf(wj4, __uint_as_float(u << 16),         1.f)), a0);
      a0 = fmaf(m2vw[5], frcp(fmaf(wj5, __uint_as_float(u & 0xffff0000u), 1.f)), a0);
      u = (unsigned)er[3];
      a0 = fmaf(m2vw[6], frcp(fmaf(wj6, __uint_as_float(u << 16),         1.f)), a0);
      a0 = fmaf(m2vw[7], frcp(fmaf(wj7, __uint_as_float(u & 0xffff0000u), 1.f)), a0);
      u = (unsigned)er[4];
      a1 = fmaf(m2vw[0], frcp(fmaf(wj0, __uint_as_float(u << 16),         1.f)), a1);
      a1 = fmaf(m2vw[1], frcp(fmaf(wj1, __uint_as_float(u & 0xffff0000u), 1.f)), a1);
      u = (unsigned)er[5];
      a1 = fmaf(m2vw[2], frcp(fmaf(wj2, __uint_as_float(u << 16),         1.f)), a1);
      a1 = fmaf(m2vw[3], frcp(fmaf(wj3, __uint_as_float(u & 0xffff0000u), 1.f)), a1);
      u = (unsigned)er[6];
      a1 = fmaf(m2vw[4], frcp(fmaf(wj4, __uint_as_float(u << 16),         1.f)), a1);
      a1 = fmaf(m2vw[5], frcp(fmaf(wj5, __uint_as_float(u & 0xffff0000u), 1.f)), a1);
      u = (unsigned)er[7];
      a1 = fmaf(m2vw[6], frcp(fmaf(wj6, __uint_as_float(u << 16),         1.f)), a1);
      a1 = fmaf(m2vw[7], frcp(fmaf(wj7, __uint_as_float(u & 0xffff0000u), 1.f)), a1);
      a0 = sum16(a0);
      a1 = sum16(a1);
      const float e0 = fexp2(L2E * a0);
      const float e1 = fexp2(L2E * a1);
      float ps = e0 + e1;
      ps += __int_as_float(__builtin_amdgcn_ds_swizzle(__float_as_int(ps), 0x401F)); // xor16
      ps += __shfl_xor(ps, 32);
      if (lane == 0) part[wid] = ps;
      if (s_l == 0) {
        xpad[wid][2 * dp]     = e0 * xh[t][d0];
        xpad[wid][2 * dp + 1] = e1 * xh[t][d0 + 1];
      }
    }
    __syncthreads();

    // ---- D+E: gates + LSTM cell (4 gates per lane, DPP reduce)
    {
      float tot = part[lane & 15];
      tot = sum16(tot);
      const float rs = frcp(tot);
      const float4 x0 = *reinterpret_cast<const float4*>(&xpad[cD][0]);
      const float4 x1 = *reinterpret_cast<const float4*>(&xpad[cD][4]);
      const float4 h4 = *reinterpret_cast<const float4*>(&hq[p][cD][0]);
      const float xs0 = x0.x * rs, xs1 = x0.y * rs, xs2 = x0.z * rs, xs3 = x0.w * rs;
      const float xs4 = x1.x * rs, xs5 = x1.y * rs, xs6 = x1.z * rs, xs7 = x1.w * rs;
      float ac[4];
#pragma unroll
      for (int g = 0; g < 4; ++g) {
        float a = 0.f;
        a = fmaf(xs0, wxr[g][0], a);
        a = fmaf(xs1, wxr[g][1], a);
        a = fmaf(xs2, wxr[g][2], a);
        a = fmaf(xs3, wxr[g][3], a);
        a = fmaf(xs4, wxr[g][4], a);
        a = fmaf(xs5, wxr[g][5], a);
        a = fmaf(xs6, wxr[g][6], a);
        a = fmaf(xs7, wxr[g][7], a);
        a = fmaf(h4.x, whr[g][0], a);
        a = fmaf(h4.y, whr[g][1], a);
        a = fmaf(h4.z, whr[g][2], a);
        a = fmaf(h4.w, whr[g][3], a);
        ac[g] = sum16(a);
      }
      const float gi = ac[0] + b4[0];
      const float gf = ac[1] + b4[1];
      const float gG = ac[2] + b4[2];
      const float go = ac[3] + b4[3];
      const float c_old = cq[p][wid][kk];
      const float si = frcp(1.f + fexp2(-L2E * gi));
      const float sf = frcp(1.f + fexp2(-L2E * gf));
      const float tg = 1.f - 2.f * frcp(1.f + fexp2(C2 * gG));
      const float cn = fmaf(sf, c_old, si * tg);
      const float so = frcp(1.f + fexp2(-L2E * go));
      const float tc = 1.f - 2.f * frcp(1.f + fexp2(C2 * cn));
      const float hn = so * tc;
      if (cD == 0) {
        hq[p ^ 1][wid][kk] = hn;
        cq[p ^ 1][wid][kk] = cn;
        hbuf[t][kD] = hn;
      }
      if (wid == 0) {   // x_hat output row (in-place over consumed x row)
        const float exa = xpad[lane >> 3][lane & 7];
        const float exb = xpad[8 + (lane >> 3)][lane & 7];
        xh[t][lane]      = exa * rs;
        xh[t][lane + 64] = exb * rs;
      }
    }
    __syncthreads();
    p ^= 1;
  }

  // ---------------- bulk flush of outputs -----------------------------------
#pragma unroll
  for (int i = 0; i < 4; ++i) {
    const int f = i * 1024 + tid;
    const int t = f >> 5, c = (f & 31) << 2;
    *reinterpret_cast<float4*>(out + b * (NT * ND) + t * ND + c) =
        *reinterpret_cast<const float4*>(&xh[t][c]);
  }
  float* out2 = out + NB * (NT * ND) + b * (NT * NH);
#pragma unroll
  for (int i = 0; i < 2; ++i) {
    const int f = i * 1024 + tid;
    const int t = f >> 4, c = (f & 15) << 2;
    *reinterpret_cast<float4*>(out2 + t * NH + c) =
        *reinterpret_cast<const float4*>(&hbuf[t][c]);
  }
}

extern "C" void kernel_launch(void* const* d_in, const int* in_sizes, int n_in,
                              void* d_out, int out_size, void* d_ws, size_t ws_size,
                              hipStream_t stream) {
  const float* x    = (const float*)d_in[0];
  const float* Wehs = (const float*)d_in[1];
  const float* behs = (const float*)d_in[2];
  const float* Ue   = (const float*)d_in[3];
  const float* Ueb  = (const float*)d_in[4];
  const float* vew  = (const float*)d_in[5];
  // d_in[6] = v_e_b: constant shift before softmax -> no effect, unused.
  const float* Wih  = (const float*)d_in[7];
  const float* Whh  = (const float*)d_in[8];
  const float* bih  = (const float*)d_in[9];
  const float* bhh  = (const float*)d_in[10];
  float* out = (float*)d_out;

  darnn_enc<<<NB, NTH, 0, stream>>>(x, Wehs, behs, Ue, Ueb, vew, Wih, Whh, bih, bhh, out);
}

// Round 6
// 386.912 us; speedup vs baseline: 1.0022x; 1.0022x over previous
//
#include <hip/hip_runtime.h>
#include <hip/hip_bf16.h>

#define NB 128      // batch
#define NT 128      // Tm1
#define ND 128      // input size (drivers)
#define NH 64       // hidden
#define NTH 1024    // threads per block
#define ESTR 144    // Ebt row stride (ushorts)

__device__ __forceinline__ float fexp2(float x) { return __builtin_amdgcn_exp2f(x); }
__device__ __forceinline__ float frcp (float x) { return __builtin_amdgcn_rcpf(x); }

// DPP-based partial-sum add: v += lane-permuted(v)
template<int CTRL>
__device__ __forceinline__ float dppadd(float v) {
  return v + __int_as_float(__builtin_amdgcn_update_dpp(
      0, __float_as_int(v), CTRL, 0xF, 0xF, true));
}
// sum over each 16-lane group
__device__ __forceinline__ float sum16(float v) {
  v = dppadd<0xB1>(v);   // quad_perm [1,0,3,2]
  v = dppadd<0x4E>(v);   // quad_perm [2,3,0,1]
  v = dppadd<0x141>(v);  // row_half_mirror
  v = dppadd<0x140>(v);  // row_mirror
  return v;
}

// f32 -> bf16 bits, round-to-nearest-even
__device__ __forceinline__ unsigned short f2bf(float f) {
  unsigned u = __float_as_uint(f);
  u += 0x7fffu + ((u >> 16) & 1u);
  return (unsigned short)(u >> 16);
}
__device__ __forceinline__ unsigned pack2(float lo, float hi) {
  return (unsigned)f2bf(lo) | ((unsigned)f2bf(hi) << 16);
}
__device__ __forceinline__ float blo(unsigned u) { return __uint_as_float(u << 16); }
__device__ __forceinline__ float bhi(unsigned u) { return __uint_as_float(u & 0xffff0000u); }

// Pin a value into a VGPR: an asm-redefined value cannot be rematerialized
// as a (global/LDS) load, so the weights stay register/AGPR-resident across
// the 128-step loop instead of being re-streamed from L2 every step.
#define PIN(v) asm volatile("" : "+v"(v))

__global__ __launch_bounds__(NTH)
__attribute__((amdgpu_waves_per_eu(4, 4)))
void darnn_enc(
    const float* __restrict__ x,     // [B][T1][D]
    const float* __restrict__ Wehs,  // [T1][2H]
    const float* __restrict__ behs,  // [T1]
    const float* __restrict__ Ue,    // [T1][T1]
    const float* __restrict__ Ueb,   // [T1]
    const float* __restrict__ vew,   // [T1]
    const float* __restrict__ Wih,   // [4H][D]
    const float* __restrict__ Whh,   // [4H][H]
    const float* __restrict__ bih,   // [256]
    const float* __restrict__ bhh,   // [256]
    float* __restrict__ out)
{
  constexpr float C2  = 2.88539008177792681f;  // 2*log2(e)
  constexpr float L2E = 1.44269504088896340f;  // log2(e)

  __shared__ __align__(16) float          xh[NT][ND];     // 64K: x, overwritten by x_hat
  __shared__ __align__(16) unsigned short Ebt[ND][ESTR];  // 36.9K: E bf16 (prologue)
  __shared__ __align__(16) float          hbuf[NT][NH];   // 32K: h outputs (prologue: UeTc)
  __shared__ __align__(16) float          hq[2][16][6];   // h chunks of 4, padded, dbuf
  __shared__ __align__(16) float          cq[2][16][6];   // c chunks of 4, padded, dbuf
  __shared__ __align__(16) float          wvm[16][20];    // [0:8)=w_s dyn, [8:16)=-2*vew static
  __shared__ __align__(16) float          xpad[16][10];   // ex = e*x chunks of 8, padded
  __shared__ __align__(16) float          part[16];       // per-wave sum of e

  const int b    = blockIdx.x;
  const int tid  = threadIdx.x;
  const int lane = tid & 63;
  const int wid  = tid >> 6;
  const float* xb = x + b * (NT * ND);

  // ---------------- stage x into LDS ---------------------------------------
#pragma unroll
  for (int i = 0; i < 4; ++i) {
    const int f = i * 1024 + tid;
    const int t = f >> 5, c = (f & 31) << 2;
    *reinterpret_cast<float4*>(&xh[t][c]) =
        *reinterpret_cast<const float4*>(xb + t * ND + c);
  }
  float (*UeTc)[33] = reinterpret_cast<float(*)[33]>(&hbuf[0][0]);
  __syncthreads();

  // ---------------- Prologue: E[d][s] = exp(2*(x_perm @ Ue^T + Ueb)) --------
  {
    const int dq = tid & 31;
    const int sg = tid >> 5;
    float acc[16];
#pragma unroll
    for (int i = 0; i < 16; ++i) acc[i] = 0.f;
    for (int c = 0; c < 4; ++c) {
      {
        const int ss = 32 * c + sg;
        const int t4 = dq * 4;
        const float4 u4 = *reinterpret_cast<const float4*>(Ue + ss * NT + t4);
        UeTc[t4 + 0][sg] = u4.x;
        UeTc[t4 + 1][sg] = u4.y;
        UeTc[t4 + 2][sg] = u4.z;
        UeTc[t4 + 3][sg] = u4.w;
      }
      __syncthreads();
#pragma unroll 4
      for (int t = 0; t < NT; ++t) {
        const float4 xv = *reinterpret_cast<const float4*>(&xh[t][4 * dq]);
        const float u = UeTc[t][sg];
        acc[4*c+0] = fmaf(xv.x, u, acc[4*c+0]);
        acc[4*c+1] = fmaf(xv.y, u, acc[4*c+1]);
        acc[4*c+2] = fmaf(xv.z, u, acc[4*c+2]);
        acc[4*c+3] = fmaf(xv.w, u, acc[4*c+3]);
      }
      __syncthreads();
    }
#pragma unroll
    for (int c = 0; c < 4; ++c) {
      const int ss = sg + 32 * c;
      const float ub = Ueb[ss];
#pragma unroll
      for (int di = 0; di < 4; ++di) {
        const float e = fexp2(C2 * (acc[4*c+di] + ub));
        Ebt[4*dq + di][ss] = f2bf(e);
      }
    }
  }
  __syncthreads();   // Ebt complete before register loads

  // zero h/c state (both parities); stage -2*vew into wvm static half
  if (tid < 192) (&hq[0][0][0])[tid] = 0.f;
  if (tid < 192) (&cq[0][0][0])[tid] = 0.f;
  if (tid < 128) wvm[tid >> 3][8 + (tid & 7)] = -2.f * vew[tid];

  // ---------------- persistent per-thread registers (bf16-packed) -----------
  // phase A: 8 threads per s
  const int s_a = tid >> 3, r_a = tid & 7;
  unsigned wehs_p[8];
#pragma unroll
  for (int i = 0; i < 4; ++i) {
    const float4 v4 = *reinterpret_cast<const float4*>(Wehs + s_a * 128 + r_a * 16 + 4 * i);
    wehs_p[2*i]   = pack2(v4.x, v4.y);
    wehs_p[2*i+1] = pack2(v4.z, v4.w);
  }
  float behs_r = behs[s_a];

  // phase B: lane = s_l + 16*dp; d0 = 8*wid + 2*dp
  const int s_l = lane & 15;
  const int dp  = lane >> 4;
  const int d0  = 8 * wid + 2 * dp;
  // E fragments (bf16 pairs), time-invariant
  int er[8];
  {
    const int4 ea = *reinterpret_cast<const int4*>(&Ebt[d0][8 * s_l]);
    const int4 eb = *reinterpret_cast<const int4*>(&Ebt[d0 + 1][8 * s_l]);
    er[0] = ea.x; er[1] = ea.y; er[2] = ea.z; er[3] = ea.w;
    er[4] = eb.x; er[5] = eb.y; er[6] = eb.z; er[7] = eb.w;
  }

  // phase D+E: lane = 16*kk + cD; unit kD = 4*wid + kk; all 4 gates per lane
  const int kk = lane >> 4, cD = lane & 15;
  const int kD = 4 * wid + kk;
  unsigned wxr_p[16], whr_p[8];
  float b4[4];
#pragma unroll
  for (int g = 0; g < 4; ++g) {
    const int j = 64 * g + kD;
    const float4 u0 = *reinterpret_cast<const float4*>(Wih + j * 128 + 8 * cD);
    const float4 u1 = *reinterpret_cast<const float4*>(Wih + j * 128 + 8 * cD + 4);
    wxr_p[4*g]   = pack2(u0.x, u0.y);
    wxr_p[4*g+1] = pack2(u0.z, u0.w);
    wxr_p[4*g+2] = pack2(u1.x, u1.y);
    wxr_p[4*g+3] = pack2(u1.z, u1.w);
    const float4 u2 = *reinterpret_cast<const float4*>(Whh + j * 64 + 4 * cD);
    whr_p[2*g]   = pack2(u2.x, u2.y);
    whr_p[2*g+1] = pack2(u2.z, u2.w);
    b4[g] = bih[j] + bhh[j];
  }

  // pin all persistent words: blocks load-rematerialization across the loop
#pragma unroll
  for (int i = 0; i < 8; ++i) PIN(wehs_p[i]);
#pragma unroll
  for (int i = 0; i < 8; ++i) PIN(er[i]);
#pragma unroll
  for (int i = 0; i < 16; ++i) PIN(wxr_p[i]);
#pragma unroll
  for (int i = 0; i < 8; ++i) PIN(whr_p[i]);
#pragma unroll
  for (int g = 0; g < 4; ++g) PIN(b4[g]);
  PIN(behs_r);

  __syncthreads();

  // ---------------- main recurrence: 3 barriers/step, no global mem ---------
  int p = 0;
  for (int t = 0; t < NT; ++t) {
    // ---- A: we[s] = behs[s] + hc . Wehs[s,:];  w_s = exp(2*we)
    {
      const float* src = (r_a < 4) ? &hq[p][4 * (r_a & 3)][0] : &cq[p][4 * (r_a & 3)][0];
      float a0 = 0.f;
#pragma unroll
      for (int i = 0; i < 4; ++i) {
        const float4 h4 = *reinterpret_cast<const float4*>(src + 6 * i);
        const unsigned w0 = wehs_p[2*i], w1 = wehs_p[2*i+1];
        a0 = fmaf(h4.x, blo(w0), a0);
        a0 = fmaf(h4.y, bhi(w0), a0);
        a0 = fmaf(h4.z, blo(w1), a0);
        a0 = fmaf(h4.w, bhi(w1), a0);
      }
      a0 = dppadd<0xB1>(a0);
      a0 = dppadd<0x4E>(a0);
      a0 = dppadd<0x141>(a0);
      if (r_a == 0) wvm[s_a >> 3][s_a & 7] = fexp2(C2 * (a0 + behs_r));
    }
    __syncthreads();

    // ---- B': v[d] -> e[d] = exp(v); writers stage ex = e*x; wave partial Σe
    {
      const float4 wa = *reinterpret_cast<const float4*>(&wvm[s_l][0]);
      const float4 wb = *reinterpret_cast<const float4*>(&wvm[s_l][4]);
      const float4 ma = *reinterpret_cast<const float4*>(&wvm[s_l][8]);
      const float4 mb = *reinterpret_cast<const float4*>(&wvm[s_l][12]);
      float a0 = 0.f, a1 = 0.f;
      unsigned u;
      u = (unsigned)er[0];
      a0 = fmaf(ma.x, frcp(fmaf(wa.x, blo(u), 1.f)), a0);
      a0 = fmaf(ma.y, frcp(fmaf(wa.y, bhi(u), 1.f)), a0);
      u = (unsigned)er[1];
      a0 = fmaf(ma.z, frcp(fmaf(wa.z, blo(u), 1.f)), a0);
      a0 = fmaf(ma.w, frcp(fmaf(wa.w, bhi(u), 1.f)), a0);
      u = (unsigned)er[2];
      a0 = fmaf(mb.x, frcp(fmaf(wb.x, blo(u), 1.f)), a0);
      a0 = fmaf(mb.y, frcp(fmaf(wb.y, bhi(u), 1.f)), a0);
      u = (unsigned)er[3];
      a0 = fmaf(mb.z, frcp(fmaf(wb.z, blo(u), 1.f)), a0);
      a0 = fmaf(mb.w, frcp(fmaf(wb.w, bhi(u), 1.f)), a0);
      u = (unsigned)er[4];
      a1 = fmaf(ma.x, frcp(fmaf(wa.x, blo(u), 1.f)), a1);
      a1 = fmaf(ma.y, frcp(fmaf(wa.y, bhi(u), 1.f)), a1);
      u = (unsigned)er[5];
      a1 = fmaf(ma.z, frcp(fmaf(wa.z, blo(u), 1.f)), a1);
      a1 = fmaf(ma.w, frcp(fmaf(wa.w, bhi(u), 1.f)), a1);
      u = (unsigned)er[6];
      a1 = fmaf(mb.x, frcp(fmaf(wb.x, blo(u), 1.f)), a1);
      a1 = fmaf(mb.y, frcp(fmaf(wb.y, bhi(u), 1.f)), a1);
      u = (unsigned)er[7];
      a1 = fmaf(mb.z, frcp(fmaf(wb.z, blo(u), 1.f)), a1);
      a1 = fmaf(mb.w, frcp(fmaf(wb.w, bhi(u), 1.f)), a1);
      a0 = sum16(a0);
      a1 = sum16(a1);
      const float e0 = fexp2(L2E * a0);
      const float e1 = fexp2(L2E * a1);
      float ps = e0 + e1;
      ps += __int_as_float(__builtin_amdgcn_ds_swizzle(__float_as_int(ps), 0x401F)); // xor16
      ps += __shfl_xor(ps, 32);
      if (lane == 0) part[wid] = ps;
      if (s_l == 0) {
        xpad[wid][2 * dp]     = e0 * xh[t][d0];
        xpad[wid][2 * dp + 1] = e1 * xh[t][d0 + 1];
      }
    }
    __syncthreads();

    // ---- D+E: gates + LSTM cell (4 gates per lane, DPP reduce)
    {
      float tot = part[lane & 15];
      tot = sum16(tot);
      const float rs = frcp(tot);
      const float4 x0 = *reinterpret_cast<const float4*>(&xpad[cD][0]);
      const float4 x1 = *reinterpret_cast<const float4*>(&xpad[cD][4]);
      const float4 h4 = *reinterpret_cast<const float4*>(&hq[p][cD][0]);
      const float xs0 = x0.x * rs, xs1 = x0.y * rs, xs2 = x0.z * rs, xs3 = x0.w * rs;
      const float xs4 = x1.x * rs, xs5 = x1.y * rs, xs6 = x1.z * rs, xs7 = x1.w * rs;
      float ac[4];
#pragma unroll
      for (int g = 0; g < 4; ++g) {
        const unsigned W0 = wxr_p[4*g], W1 = wxr_p[4*g+1];
        const unsigned W2 = wxr_p[4*g+2], W3 = wxr_p[4*g+3];
        const unsigned H0 = whr_p[2*g], H1 = whr_p[2*g+1];
        float a = xs0 * blo(W0);
        a = fmaf(xs1, bhi(W0), a);
        a = fmaf(xs2, blo(W1), a);
        a = fmaf(xs3, bhi(W1), a);
        a = fmaf(xs4, blo(W2), a);
        a = fmaf(xs5, bhi(W2), a);
        a = fmaf(xs6, blo(W3), a);
        a = fmaf(xs7, bhi(W3), a);
        a = fmaf(h4.x, blo(H0), a);
        a = fmaf(h4.y, bhi(H0), a);
        a = fmaf(h4.z, blo(H1), a);
        a = fmaf(h4.w, bhi(H1), a);
        ac[g] = sum16(a);
      }
      const float gi = ac[0] + b4[0];
      const float gf = ac[1] + b4[1];
      const float gG = ac[2] + b4[2];
      const float go = ac[3] + b4[3];
      const float c_old = cq[p][wid][kk];
      const float si = frcp(1.f + fexp2(-L2E * gi));
      const float sf = frcp(1.f + fexp2(-L2E * gf));
      const float tg = 1.f - 2.f * frcp(1.f + fexp2(C2 * gG));
      const float cn = fmaf(sf, c_old, si * tg);
      const float so = frcp(1.f + fexp2(-L2E * go));
      const float tc = 1.f - 2.f * frcp(1.f + fexp2(C2 * cn));
      const float hn = so * tc;
      if (cD == 0) {
        hq[p ^ 1][wid][kk] = hn;
        cq[p ^ 1][wid][kk] = cn;
        hbuf[t][kD] = hn;
      }
      if (wid == 0) {   // x_hat output row (in-place over consumed x row)
        const float exa = xpad[lane >> 3][lane & 7];
        const float exb = xpad[8 + (lane >> 3)][lane & 7];
        xh[t][lane]      = exa * rs;
        xh[t][lane + 64] = exb * rs;
      }
    }
    __syncthreads();
    p ^= 1;
  }

  // ---------------- bulk flush of outputs -----------------------------------
#pragma unroll
  for (int i = 0; i < 4; ++i) {
    const int f = i * 1024 + tid;
    const int t = f >> 5, c = (f & 31) << 2;
    *reinterpret_cast<float4*>(out + b * (NT * ND) + t * ND + c) =
        *reinterpret_cast<const float4*>(&xh[t][c]);
  }
  float* out2 = out + NB * (NT * ND) + b * (NT * NH);
#pragma unroll
  for (int i = 0; i < 2; ++i) {
    const int f = i * 1024 + tid;
    const int t = f >> 4, c = (f & 15) << 2;
    *reinterpret_cast<float4*>(out2 + t * NH + c) =
        *reinterpret_cast<const float4*>(&hbuf[t][c]);
  }
}

extern "C" void kernel_launch(void* const* d_in, const int* in_sizes, int n_in,
                              void* d_out, int out_size, void* d_ws, size_t ws_size,
                              hipStream_t stream) {
  const float* x    = (const float*)d_in[0];
  const float* Wehs = (const float*)d_in[1];
  const float* behs = (const float*)d_in[2];
  const float* Ue   = (const float*)d_in[3];
  const float* Ueb  = (const float*)d_in[4];
  const float* vew  = (const float*)d_in[5];
  // d_in[6] = v_e_b: constant shift before softmax -> no effect, unused.
  const float* Wih  = (const float*)d_in[7];
  const float* Whh  = (const float*)d_in[8];
  const float* bih  = (const float*)d_in[9];
  const float* bhh  = (const float*)d_in[10];
  float* out = (float*)d_out;

  darnn_enc<<<NB, NTH, 0, stream>>>(x, Wehs, behs, Ue, Ueb, vew, Wih, Whh, bih, bhh, out);
}

// Round 7
// 304.395 us; speedup vs baseline: 1.2739x; 1.2711x over previous
//
#include <hip/hip_runtime.h>
#include <hip/hip_bf16.h>
#include <hip/hip_fp16.h>

#define NB 128      // batch
#define NT 128      // Tm1
#define ND 128      // input size (drivers)
#define NH 64       // hidden
#define NTH 1024    // threads per block
#define ESTR 144    // Ebt row stride (ushorts)

__device__ __forceinline__ float fexp2(float x) { return __builtin_amdgcn_exp2f(x); }
__device__ __forceinline__ float frcp (float x) { return __builtin_amdgcn_rcpf(x); }

template<int CTRL>
__device__ __forceinline__ float dppadd(float v) {
  return v + __int_as_float(__builtin_amdgcn_update_dpp(
      0, __float_as_int(v), CTRL, 0xF, 0xF, true));
}
__device__ __forceinline__ float sum16(float v) {
  v = dppadd<0xB1>(v);   // quad_perm [1,0,3,2]
  v = dppadd<0x4E>(v);   // quad_perm [2,3,0,1]
  v = dppadd<0x141>(v);  // row_half_mirror
  v = dppadd<0x140>(v);  // row_mirror
  return v;
}

// f32 -> bf16 bits, round-to-nearest-even
__device__ __forceinline__ unsigned short f2bf(float f) {
  unsigned u = __float_as_uint(f);
  u += 0x7fffu + ((u >> 16) & 1u);
  return (unsigned short)(u >> 16);
}
__device__ __forceinline__ float blo(unsigned u) { return __uint_as_float(u << 16); }
__device__ __forceinline__ float bhi(unsigned u) { return __uint_as_float(u & 0xffff0000u); }

// u32 <-> __half2 bit casts
__device__ __forceinline__ __half2 uh(unsigned u) {
  union { unsigned u; __half2 h; } x; x.u = u; return x.h;
}
__device__ __forceinline__ unsigned hu(__half2 h) {
  union { unsigned u; __half2 h; } x; x.h = h; return x.u;
}
__device__ __forceinline__ unsigned pkf16(float lo, float hi) {
  return hu(__halves2half2(__float2half_rn(lo), __float2half_rn(hi)));
}

#define PIN(v) asm volatile("" : "+v"(v))

__global__ __launch_bounds__(NTH)
__attribute__((amdgpu_waves_per_eu(4, 4)))
void darnn_enc(
    const float* __restrict__ x,     // [B][T1][D]
    const float* __restrict__ Wehs,  // [T1][2H]
    const float* __restrict__ behs,  // [T1]
    const float* __restrict__ Ue,    // [T1][T1]
    const float* __restrict__ Ueb,   // [T1]
    const float* __restrict__ vew,   // [T1]
    const float* __restrict__ Wih,   // [4H][D]
    const float* __restrict__ Whh,   // [4H][H]
    const float* __restrict__ bih,   // [256]
    const float* __restrict__ bhh,   // [256]
    float* __restrict__ out)
{
  constexpr float C2  = 2.88539008177792681f;  // 2*log2(e)
  constexpr float L2E = 1.44269504088896340f;  // log2(e)

  __shared__ __align__(16) float          xh[NT][ND];     // 64K: x, overwritten by x_hat
  __shared__ __align__(16) unsigned short Ebt[ND][ESTR];  // 36.9K: E bf16 (prologue)
  __shared__ __align__(16) float          hbuf[NT][NH];   // 32K: h outputs (prologue: UeTc)
  __shared__ __align__(16) unsigned       hcpk[2][8][12]; // [h|c] as half2, 16 vals/row, dbuf
  __shared__ __align__(16) float          cq[2][16][6];   // c f32 (cell state), dbuf
  __shared__ __align__(16) float          wvm[16][12];    // w_s = exp(2*we), 8/row
  __shared__ __align__(16) unsigned       xpk[16][12];    // e*x as half2, 8 vals/row (4 u32)
  __shared__ __align__(16) float          part[16];       // per-wave sum of e

  const int b    = blockIdx.x;
  const int tid  = threadIdx.x;
  const int lane = tid & 63;
  const int wid  = tid >> 6;
  const float* xb = x + b * (NT * ND);

  // ---------------- stage x into LDS ---------------------------------------
#pragma unroll
  for (int i = 0; i < 4; ++i) {
    const int f = i * 1024 + tid;
    const int t = f >> 5, c = (f & 31) << 2;
    *reinterpret_cast<float4*>(&xh[t][c]) =
        *reinterpret_cast<const float4*>(xb + t * ND + c);
  }
  float (*UeTc)[33] = reinterpret_cast<float(*)[33]>(&hbuf[0][0]);
  __syncthreads();

  // ---------------- Prologue: E[d][s] = exp(2*(x_perm @ Ue^T + Ueb)) --------
  {
    const int dq = tid & 31;
    const int sg = tid >> 5;
    float acc[16];
#pragma unroll
    for (int i = 0; i < 16; ++i) acc[i] = 0.f;
    for (int c = 0; c < 4; ++c) {
      {
        const int ss = 32 * c + sg;
        const int t4 = dq * 4;
        const float4 u4 = *reinterpret_cast<const float4*>(Ue + ss * NT + t4);
        UeTc[t4 + 0][sg] = u4.x;
        UeTc[t4 + 1][sg] = u4.y;
        UeTc[t4 + 2][sg] = u4.z;
        UeTc[t4 + 3][sg] = u4.w;
      }
      __syncthreads();
#pragma unroll 4
      for (int t = 0; t < NT; ++t) {
        const float4 xv = *reinterpret_cast<const float4*>(&xh[t][4 * dq]);
        const float u = UeTc[t][sg];
        acc[4*c+0] = fmaf(xv.x, u, acc[4*c+0]);
        acc[4*c+1] = fmaf(xv.y, u, acc[4*c+1]);
        acc[4*c+2] = fmaf(xv.z, u, acc[4*c+2]);
        acc[4*c+3] = fmaf(xv.w, u, acc[4*c+3]);
      }
      __syncthreads();
    }
#pragma unroll
    for (int c = 0; c < 4; ++c) {
      const int ss = sg + 32 * c;
      const float ub = Ueb[ss];
#pragma unroll
      for (int di = 0; di < 4; ++di) {
        const float e = fexp2(C2 * (acc[4*c+di] + ub));
        Ebt[4*dq + di][ss] = f2bf(e);
      }
    }
  }
  __syncthreads();   // Ebt complete before register loads

  // zero h/c state (both parities)
  if (tid < 192) (&hcpk[0][0][0])[tid] = 0u;          // half2(0,0)
  if (tid < 192) (&cq[0][0][0])[tid] = 0.f;

  // ---------------- persistent per-thread registers -------------------------
  // phase A: 8 threads per s; 16 hc-inputs per thread as 8 half2
  const int s_a = tid >> 3, r_a = tid & 7;
  unsigned wehs_p[8];
#pragma unroll
  for (int i = 0; i < 4; ++i) {
    const float4 v4 = *reinterpret_cast<const float4*>(Wehs + s_a * 128 + r_a * 16 + 4 * i);
    wehs_p[2*i]   = pkf16(v4.x, v4.y);
    wehs_p[2*i+1] = pkf16(v4.z, v4.w);
  }
  float behs_r = behs[s_a];

  // phase B: lane = s_l + 16*dp; d0 = 8*wid + 2*dp
  const int s_l = lane & 15;
  const int dp  = lane >> 4;
  const int d0  = 8 * wid + 2 * dp;
  float m2vw[8];
  {
    const float4 va = *reinterpret_cast<const float4*>(vew + 8 * s_l);
    const float4 vb = *reinterpret_cast<const float4*>(vew + 8 * s_l + 4);
    m2vw[0] = -2.f * va.x; m2vw[1] = -2.f * va.y; m2vw[2] = -2.f * va.z; m2vw[3] = -2.f * va.w;
    m2vw[4] = -2.f * vb.x; m2vw[5] = -2.f * vb.y; m2vw[6] = -2.f * vb.z; m2vw[7] = -2.f * vb.w;
  }
  // E fragments (bf16 pairs), time-invariant
  int er[8];
  {
    const int4 ea = *reinterpret_cast<const int4*>(&Ebt[d0][8 * s_l]);
    const int4 eb = *reinterpret_cast<const int4*>(&Ebt[d0 + 1][8 * s_l]);
    er[0] = ea.x; er[1] = ea.y; er[2] = ea.z; er[3] = ea.w;
    er[4] = eb.x; er[5] = eb.y; er[6] = eb.z; er[7] = eb.w;
  }

  // phase D+E: lane = 16*kk + cD; unit kD = 4*wid + kk; 4 gates per lane
  const int kk = lane >> 4, cD = lane & 15;
  const int kD = 4 * wid + kk;
  unsigned wx2[16], wh2[8];   // half2-packed gate weights
  float b4[4];
#pragma unroll
  for (int g = 0; g < 4; ++g) {
    const int j = 64 * g + kD;
    const float4 u0 = *reinterpret_cast<const float4*>(Wih + j * 128 + 8 * cD);
    const float4 u1 = *reinterpret_cast<const float4*>(Wih + j * 128 + 8 * cD + 4);
    wx2[4*g]   = pkf16(u0.x, u0.y);
    wx2[4*g+1] = pkf16(u0.z, u0.w);
    wx2[4*g+2] = pkf16(u1.x, u1.y);
    wx2[4*g+3] = pkf16(u1.z, u1.w);
    const float4 u2 = *reinterpret_cast<const float4*>(Whh + j * 64 + 4 * cD);
    wh2[2*g]   = pkf16(u2.x, u2.y);
    wh2[2*g+1] = pkf16(u2.z, u2.w);
    b4[g] = bih[j] + bhh[j];
  }

#pragma unroll
  for (int i = 0; i < 8; ++i) PIN(wehs_p[i]);
#pragma unroll
  for (int i = 0; i < 8; ++i) PIN(er[i]);
#pragma unroll
  for (int i = 0; i < 16; ++i) PIN(wx2[i]);
#pragma unroll
  for (int i = 0; i < 8; ++i) PIN(wh2[i]);
#pragma unroll
  for (int g = 0; g < 4; ++g) PIN(b4[g]);
#pragma unroll
  for (int i = 0; i < 8; ++i) PIN(m2vw[i]);
  PIN(behs_r);

  __syncthreads();

  // ---------------- main recurrence: 3 barriers/step, no global mem ---------
  int p = 0;
  for (int t = 0; t < NT; ++t) {
    // ---- A: we[s] = behs[s] + hc . Wehs[s,:];  w_s = exp(2*we)  (pk f16)
    {
      const int4 q0 = *reinterpret_cast<const int4*>(&hcpk[p][r_a][0]);
      const int4 q1 = *reinterpret_cast<const int4*>(&hcpk[p][r_a][4]);
      __half2 ac0 = uh(0u), ac1 = uh(0u);
      ac0 = __hfma2(uh((unsigned)q0.x), uh(wehs_p[0]), ac0);
      ac1 = __hfma2(uh((unsigned)q0.y), uh(wehs_p[1]), ac1);
      ac0 = __hfma2(uh((unsigned)q0.z), uh(wehs_p[2]), ac0);
      ac1 = __hfma2(uh((unsigned)q0.w), uh(wehs_p[3]), ac1);
      ac0 = __hfma2(uh((unsigned)q1.x), uh(wehs_p[4]), ac0);
      ac1 = __hfma2(uh((unsigned)q1.y), uh(wehs_p[5]), ac1);
      ac0 = __hfma2(uh((unsigned)q1.z), uh(wehs_p[6]), ac0);
      ac1 = __hfma2(uh((unsigned)q1.w), uh(wehs_p[7]), ac1);
      float a0 = (__low2float(ac0) + __high2float(ac0)) +
                 (__low2float(ac1) + __high2float(ac1));
      a0 = dppadd<0xB1>(a0);
      a0 = dppadd<0x4E>(a0);
      a0 = dppadd<0x141>(a0);
      if (r_a == 0) wvm[s_a >> 3][s_a & 7] = fexp2(C2 * (a0 + behs_r));
    }
    __syncthreads();

    // ---- B': v[d] -> e[d] = exp(v); writers stage e*x (half2); wave Σe
    {
      const float4 wa = *reinterpret_cast<const float4*>(&wvm[s_l][0]);
      const float4 wb = *reinterpret_cast<const float4*>(&wvm[s_l][4]);
      float a0 = 0.f, a0b = 0.f, a1 = 0.f, a1b = 0.f;
      unsigned u;
      u = (unsigned)er[0];
      a0  = fmaf(m2vw[0], frcp(fmaf(wa.x, blo(u), 1.f)), a0);
      a0b = fmaf(m2vw[1], frcp(fmaf(wa.y, bhi(u), 1.f)), a0b);
      u = (unsigned)er[1];
      a0  = fmaf(m2vw[2], frcp(fmaf(wa.z, blo(u), 1.f)), a0);
      a0b = fmaf(m2vw[3], frcp(fmaf(wa.w, bhi(u), 1.f)), a0b);
      u = (unsigned)er[2];
      a0  = fmaf(m2vw[4], frcp(fmaf(wb.x, blo(u), 1.f)), a0);
      a0b = fmaf(m2vw[5], frcp(fmaf(wb.y, bhi(u), 1.f)), a0b);
      u = (unsigned)er[3];
      a0  = fmaf(m2vw[6], frcp(fmaf(wb.z, blo(u), 1.f)), a0);
      a0b = fmaf(m2vw[7], frcp(fmaf(wb.w, bhi(u), 1.f)), a0b);
      u = (unsigned)er[4];
      a1  = fmaf(m2vw[0], frcp(fmaf(wa.x, blo(u), 1.f)), a1);
      a1b = fmaf(m2vw[1], frcp(fmaf(wa.y, bhi(u), 1.f)), a1b);
      u = (unsigned)er[5];
      a1  = fmaf(m2vw[2], frcp(fmaf(wa.z, blo(u), 1.f)), a1);
      a1b = fmaf(m2vw[3], frcp(fmaf(wa.w, bhi(u), 1.f)), a1b);
      u = (unsigned)er[6];
      a1  = fmaf(m2vw[4], frcp(fmaf(wb.x, blo(u), 1.f)), a1);
      a1b = fmaf(m2vw[5], frcp(fmaf(wb.y, bhi(u), 1.f)), a1b);
      u = (unsigned)er[7];
      a1  = fmaf(m2vw[6], frcp(fmaf(wb.z, blo(u), 1.f)), a1);
      a1b = fmaf(m2vw[7], frcp(fmaf(wb.w, bhi(u), 1.f)), a1b);
      float s0 = sum16(a0 + a0b);
      float s1 = sum16(a1 + a1b);
      const float e0 = fexp2(L2E * s0);
      const float e1 = fexp2(L2E * s1);
      float ps = e0 + e1;
      ps += __int_as_float(__builtin_amdgcn_ds_swizzle(__float_as_int(ps), 0x401F)); // xor16
      ps += __shfl_xor(ps, 32);
      if (lane == 0) part[wid] = ps;
      if (s_l == 0) {
        const float2 xv = *reinterpret_cast<const float2*>(&xh[t][d0]);
        xpk[wid][dp] = pkf16(e0 * xv.x, e1 * xv.y);
      }
    }
    __syncthreads();

    // ---- D+E: gates (pk f16, rs hoisted) + LSTM cell
    {
      float tot = part[lane & 15];
      tot = sum16(tot);
      const float rs = frcp(tot);
      const int4 xq = *reinterpret_cast<const int4*>(&xpk[cD][0]);
      const int2 hh = *reinterpret_cast<const int2*>(&hcpk[p][cD >> 2][2 * (cD & 3)]);
      const __half2 x01 = uh((unsigned)xq.x), x23 = uh((unsigned)xq.y);
      const __half2 x45 = uh((unsigned)xq.z), x67 = uh((unsigned)xq.w);
      const __half2 h01 = uh((unsigned)hh.x), h23 = uh((unsigned)hh.y);
      float ac[4];
#pragma unroll
      for (int g = 0; g < 4; ++g) {
        __half2 ax = uh(0u), ah = uh(0u);
        ax = __hfma2(x01, uh(wx2[4*g]),   ax);
        ah = __hfma2(h01, uh(wh2[2*g]),   ah);
        ax = __hfma2(x23, uh(wx2[4*g+1]), ax);
        ah = __hfma2(h23, uh(wh2[2*g+1]), ah);
        ax = __hfma2(x45, uh(wx2[4*g+2]), ax);
        ax = __hfma2(x67, uh(wx2[4*g+3]), ax);
        const float fx = __low2float(ax) + __high2float(ax);
        const float fh = __low2float(ah) + __high2float(ah);
        ac[g] = sum16(fmaf(fx, rs, fh));
      }
      const float gi = ac[0] + b4[0];
      const float gf = ac[1] + b4[1];
      const float gG = ac[2] + b4[2];
      const float go = ac[3] + b4[3];
      const float c_old = cq[p][wid][kk];
      const float si = frcp(1.f + fexp2(-L2E * gi));
      const float sf = frcp(1.f + fexp2(-L2E * gf));
      const float tg = 1.f - 2.f * frcp(1.f + fexp2(C2 * gG));
      const float cn = fmaf(sf, c_old, si * tg);
      const float so = frcp(1.f + fexp2(-L2E * go));
      const float tc = 1.f - 2.f * frcp(1.f + fexp2(C2 * cn));
      const float hn = so * tc;
      if (cD == 0) {
        __half* Hb = reinterpret_cast<__half*>(&hcpk[p ^ 1][0][0]);
        Hb[(kD >> 4) * 24 + (kD & 15)]       = __float2half_rn(hn);
        Hb[(4 + (kD >> 4)) * 24 + (kD & 15)] = __float2half_rn(cn);
        cq[p ^ 1][wid][kk] = cn;
        hbuf[t][kD] = hn;
      }
      if (wid == 0) {   // x_hat output row (in-place over consumed x row)
        const unsigned wA = xpk[lane >> 3][(lane & 7) >> 1];
        const unsigned wB = xpk[8 + (lane >> 3)][(lane & 7) >> 1];
        const float exa = (lane & 1) ? __high2float(uh(wA)) : __low2float(uh(wA));
        const float exb = (lane & 1) ? __high2float(uh(wB)) : __low2float(uh(wB));
        xh[t][lane]      = exa * rs;
        xh[t][lane + 64] = exb * rs;
      }
    }
    __syncthreads();
    p ^= 1;
  }

  // ---------------- bulk flush of outputs -----------------------------------
#pragma unroll
  for (int i = 0; i < 4; ++i) {
    const int f = i * 1024 + tid;
    const int t = f >> 5, c = (f & 31) << 2;
    *reinterpret_cast<float4*>(out + b * (NT * ND) + t * ND + c) =
        *reinterpret_cast<const float4*>(&xh[t][c]);
  }
  float* out2 = out + NB * (NT * ND) + b * (NT * NH);
#pragma unroll
  for (int i = 0; i < 2; ++i) {
    const int f = i * 1024 + tid;
    const int t = f >> 4, c = (f & 15) << 2;
    *reinterpret_cast<float4*>(out2 + t * NH + c) =
        *reinterpret_cast<const float4*>(&hbuf[t][c]);
  }
}

extern "C" void kernel_launch(void* const* d_in, const int* in_sizes, int n_in,
                              void* d_out, int out_size, void* d_ws, size_t ws_size,
                              hipStream_t stream) {
  const float* x    = (const float*)d_in[0];
  const float* Wehs = (const float*)d_in[1];
  const float* behs = (const float*)d_in[2];
  const float* Ue   = (const float*)d_in[3];
  const float* Ueb  = (const float*)d_in[4];
  const float* vew  = (const float*)d_in[5];
  // d_in[6] = v_e_b: constant shift before softmax -> no effect, unused.
  const float* Wih  = (const float*)d_in[7];
  const float* Whh  = (const float*)d_in[8];
  const float* bih  = (const float*)d_in[9];
  const float* bhh  = (const float*)d_in[10];
  float* out = (float*)d_out;

  darnn_enc<<<NB, NTH, 0, stream>>>(x, Wehs, behs, Ue, Ueb, vew, Wih, Whh, bih, bhh, out);
}

// Round 8
// 288.678 us; speedup vs baseline: 1.3433x; 1.0544x over previous
//
#include <hip/hip_runtime.h>
#include <hip/hip_bf16.h>
#include <hip/hip_fp16.h>

#define NB 128      // batch
#define NT 128      // Tm1
#define ND 128      // input size (drivers)
#define NH 64       // hidden
#define NTH 1024    // threads per block
#define ESTR 144    // Ebt row stride (ushorts)

__device__ __forceinline__ float fexp2(float x) { return __builtin_amdgcn_exp2f(x); }
__device__ __forceinline__ float frcp (float x) { return __builtin_amdgcn_rcpf(x); }

template<int CTRL>
__device__ __forceinline__ float dppadd(float v) {
  return v + __int_as_float(__builtin_amdgcn_update_dpp(
      0, __float_as_int(v), CTRL, 0xF, 0xF, true));
}
__device__ __forceinline__ float sum16(float v) {
  v = dppadd<0xB1>(v);   // quad_perm [1,0,3,2]
  v = dppadd<0x4E>(v);   // quad_perm [2,3,0,1]
  v = dppadd<0x141>(v);  // row_half_mirror
  v = dppadd<0x140>(v);  // row_mirror
  return v;
}

// f32 -> bf16 bits, round-to-nearest-even
__device__ __forceinline__ unsigned short f2bf(float f) {
  unsigned u = __float_as_uint(f);
  u += 0x7fffu + ((u >> 16) & 1u);
  return (unsigned short)(u >> 16);
}
__device__ __forceinline__ float blo(unsigned u) { return __uint_as_float(u << 16); }
__device__ __forceinline__ float bhi(unsigned u) { return __uint_as_float(u & 0xffff0000u); }

// u32 <-> __half2 bit casts
__device__ __forceinline__ __half2 uh(unsigned u) {
  union { unsigned u; __half2 h; } x; x.u = u; return x.h;
}
__device__ __forceinline__ unsigned hu(__half2 h) {
  union { unsigned u; __half2 h; } x; x.h = h; return x.u;
}
__device__ __forceinline__ unsigned pkf16(float lo, float hi) {
  return hu(__halves2half2(__float2half_rn(lo), __float2half_rn(hi)));
}

#define PIN(v) asm volatile("" : "+v"(v))

__global__ __launch_bounds__(NTH)
__attribute__((amdgpu_waves_per_eu(4, 4)))
void darnn_enc(
    const float* __restrict__ x,     // [B][T1][D]
    const float* __restrict__ Wehs,  // [T1][2H]
    const float* __restrict__ behs,  // [T1]
    const float* __restrict__ Ue,    // [T1][T1]
    const float* __restrict__ Ueb,   // [T1]
    const float* __restrict__ vew,   // [T1]
    const float* __restrict__ Wih,   // [4H][D]
    const float* __restrict__ Whh,   // [4H][H]
    const float* __restrict__ bih,   // [256]
    const float* __restrict__ bhh,   // [256]
    float* __restrict__ out)
{
  constexpr float C2  = 2.88539008177792681f;  // 2*log2(e)
  constexpr float L2E = 1.44269504088896340f;  // log2(e)

  __shared__ __align__(16) float          xh[NT][ND];     // 64K: x, overwritten by e*x
  __shared__ __align__(16) unsigned short Ebt[ND][ESTR];  // 36.9K: E bf16 (prologue)
  __shared__ __align__(16) float          hbuf[NT][NH];   // 32K: h outputs (prologue: UeTc)
  __shared__ __align__(16) unsigned       hcpk[2][8][12]; // [h|c] as half2, dbuf
  __shared__ __align__(16) float          cq[2][16][6];   // c f32 (cell state), dbuf
  __shared__ __align__(16) float          wvm[16][12];    // w_s = exp(2*we), 8/row
  __shared__ __align__(16) unsigned       xpk[16][12];    // e*x as half2, 8 vals/row
  __shared__ __align__(16) float          part64[64];     // per-d-pair partial sums of e
  __shared__ __align__(16) float          rsb[NT];        // 1/sum(e) per step

  const int b    = blockIdx.x;
  const int tid  = threadIdx.x;
  const int lane = tid & 63;
  const int wid  = tid >> 6;
  const float* xb = x + b * (NT * ND);

  // ---------------- stage x into LDS ---------------------------------------
#pragma unroll
  for (int i = 0; i < 4; ++i) {
    const int f = i * 1024 + tid;
    const int t = f >> 5, c = (f & 31) << 2;
    *reinterpret_cast<float4*>(&xh[t][c]) =
        *reinterpret_cast<const float4*>(xb + t * ND + c);
  }
  float (*UeTc)[33] = reinterpret_cast<float(*)[33]>(&hbuf[0][0]);
  __syncthreads();

  // ---------------- Prologue: E[d][s] = exp(2*(x_perm @ Ue^T + Ueb)) --------
  {
    const int dq = tid & 31;
    const int sg = tid >> 5;
    float acc[16];
#pragma unroll
    for (int i = 0; i < 16; ++i) acc[i] = 0.f;
    for (int c = 0; c < 4; ++c) {
      {
        const int ss = 32 * c + sg;
        const int t4 = dq * 4;
        const float4 u4 = *reinterpret_cast<const float4*>(Ue + ss * NT + t4);
        UeTc[t4 + 0][sg] = u4.x;
        UeTc[t4 + 1][sg] = u4.y;
        UeTc[t4 + 2][sg] = u4.z;
        UeTc[t4 + 3][sg] = u4.w;
      }
      __syncthreads();
#pragma unroll 4
      for (int t = 0; t < NT; ++t) {
        const float4 xv = *reinterpret_cast<const float4*>(&xh[t][4 * dq]);
        const float u = UeTc[t][sg];
        acc[4*c+0] = fmaf(xv.x, u, acc[4*c+0]);
        acc[4*c+1] = fmaf(xv.y, u, acc[4*c+1]);
        acc[4*c+2] = fmaf(xv.z, u, acc[4*c+2]);
        acc[4*c+3] = fmaf(xv.w, u, acc[4*c+3]);
      }
      __syncthreads();
    }
#pragma unroll
    for (int c = 0; c < 4; ++c) {
      const int ss = sg + 32 * c;
      const float ub = Ueb[ss];
#pragma unroll
      for (int di = 0; di < 4; ++di) {
        const float e = fexp2(C2 * (acc[4*c+di] + ub));
        Ebt[4*dq + di][ss] = f2bf(e);
      }
    }
  }
  __syncthreads();   // Ebt complete before register loads

  // zero h/c state (both parities)
  if (tid < 192) (&hcpk[0][0][0])[tid] = 0u;          // half2(0,0)
  if (tid < 192) (&cq[0][0][0])[tid] = 0.f;

  // ---------------- persistent per-thread registers -------------------------
  // phase A: 8 threads per s; 16 hc-inputs per thread as 8 half2
  const int s_a = tid >> 3, r_a = tid & 7;
  unsigned wehs_p[8];
#pragma unroll
  for (int i = 0; i < 4; ++i) {
    const float4 v4 = *reinterpret_cast<const float4*>(Wehs + s_a * 128 + r_a * 16 + 4 * i);
    wehs_p[2*i]   = pkf16(v4.x, v4.y);
    wehs_p[2*i+1] = pkf16(v4.z, v4.w);
  }
  float behs_r = behs[s_a];

  // phase B: lane = s_l + 16*dp; d0 = 8*wid + 2*dp
  const int s_l = lane & 15;
  const int dp  = lane >> 4;
  const int d0  = 8 * wid + 2 * dp;
  float m2vw[8];
  {
    const float4 va = *reinterpret_cast<const float4*>(vew + 8 * s_l);
    const float4 vb = *reinterpret_cast<const float4*>(vew + 8 * s_l + 4);
    m2vw[0] = -2.f * va.x; m2vw[1] = -2.f * va.y; m2vw[2] = -2.f * va.z; m2vw[3] = -2.f * va.w;
    m2vw[4] = -2.f * vb.x; m2vw[5] = -2.f * vb.y; m2vw[6] = -2.f * vb.z; m2vw[7] = -2.f * vb.w;
  }
  // E fragments (bf16 pairs), time-invariant
  int er[8];
  {
    const int4 ea = *reinterpret_cast<const int4*>(&Ebt[d0][8 * s_l]);
    const int4 eb = *reinterpret_cast<const int4*>(&Ebt[d0 + 1][8 * s_l]);
    er[0] = ea.x; er[1] = ea.y; er[2] = ea.z; er[3] = ea.w;
    er[4] = eb.x; er[5] = eb.y; er[6] = eb.z; er[7] = eb.w;
  }

  // phase D+E: lane = 16*kk + cD; unit kD = 4*wid + kk; 4 gates per lane
  const int kk = lane >> 4, cD = lane & 15;
  const int kD = 4 * wid + kk;
  unsigned wx2[16], wh2[8];   // half2-packed gate weights
  float b4[4];
#pragma unroll
  for (int g = 0; g < 4; ++g) {
    const int j = 64 * g + kD;
    const float4 u0 = *reinterpret_cast<const float4*>(Wih + j * 128 + 8 * cD);
    const float4 u1 = *reinterpret_cast<const float4*>(Wih + j * 128 + 8 * cD + 4);
    wx2[4*g]   = pkf16(u0.x, u0.y);
    wx2[4*g+1] = pkf16(u0.z, u0.w);
    wx2[4*g+2] = pkf16(u1.x, u1.y);
    wx2[4*g+3] = pkf16(u1.z, u1.w);
    const float4 u2 = *reinterpret_cast<const float4*>(Whh + j * 64 + 4 * cD);
    wh2[2*g]   = pkf16(u2.x, u2.y);
    wh2[2*g+1] = pkf16(u2.z, u2.w);
    b4[g] = bih[j] + bhh[j];
  }

#pragma unroll
  for (int i = 0; i < 8; ++i) PIN(wehs_p[i]);
#pragma unroll
  for (int i = 0; i < 8; ++i) PIN(er[i]);
#pragma unroll
  for (int i = 0; i < 16; ++i) PIN(wx2[i]);
#pragma unroll
  for (int i = 0; i < 8; ++i) PIN(wh2[i]);
#pragma unroll
  for (int g = 0; g < 4; ++g) PIN(b4[g]);
#pragma unroll
  for (int i = 0; i < 8; ++i) PIN(m2vw[i]);
  PIN(behs_r);

  __syncthreads();

  // ---------------- main recurrence: 3 barriers/step, no global mem ---------
  int p = 0;
  for (int t = 0; t < NT; ++t) {
    // prefetch x_t pair for B's writers (row t untouched until B writes it)
    const float2 xv = *reinterpret_cast<const float2*>(&xh[t][d0]);

    // ---- A: we[s] = behs[s] + hc . Wehs[s,:];  w_s = exp(2*we)  (pk f16)
    {
      const int4 q0 = *reinterpret_cast<const int4*>(&hcpk[p][r_a][0]);
      const int4 q1 = *reinterpret_cast<const int4*>(&hcpk[p][r_a][4]);
      __half2 ac0 = uh(0u), ac1 = uh(0u);
      ac0 = __hfma2(uh((unsigned)q0.x), uh(wehs_p[0]), ac0);
      ac1 = __hfma2(uh((unsigned)q0.y), uh(wehs_p[1]), ac1);
      ac0 = __hfma2(uh((unsigned)q0.z), uh(wehs_p[2]), ac0);
      ac1 = __hfma2(uh((unsigned)q0.w), uh(wehs_p[3]), ac1);
      ac0 = __hfma2(uh((unsigned)q1.x), uh(wehs_p[4]), ac0);
      ac1 = __hfma2(uh((unsigned)q1.y), uh(wehs_p[5]), ac1);
      ac0 = __hfma2(uh((unsigned)q1.z), uh(wehs_p[6]), ac0);
      ac1 = __hfma2(uh((unsigned)q1.w), uh(wehs_p[7]), ac1);
      float a0 = (__low2float(ac0) + __high2float(ac0)) +
                 (__low2float(ac1) + __high2float(ac1));
      a0 = dppadd<0xB1>(a0);
      a0 = dppadd<0x4E>(a0);
      a0 = dppadd<0x141>(a0);
      if (r_a == 0) wvm[s_a >> 3][s_a & 7] = fexp2(C2 * (a0 + behs_r));
    }
    __syncthreads();

    // ---- B': e[d] = exp(v[d]); writers stage e*x; group partial -> part64
    int2 hh; float c_old;
    {
      const float4 wa = *reinterpret_cast<const float4*>(&wvm[s_l][0]);
      const float4 wb = *reinterpret_cast<const float4*>(&wvm[s_l][4]);
      // prefetch D's inputs (stable: written by D of step t-1)
      hh    = *reinterpret_cast<const int2*>(&hcpk[p][cD >> 2][2 * (cD & 3)]);
      c_old = cq[p][wid][kk];
      float a0 = 0.f, a0b = 0.f, a1 = 0.f, a1b = 0.f;
      unsigned u;
      u = (unsigned)er[0];
      a0  = fmaf(m2vw[0], frcp(fmaf(wa.x, blo(u), 1.f)), a0);
      a0b = fmaf(m2vw[1], frcp(fmaf(wa.y, bhi(u), 1.f)), a0b);
      u = (unsigned)er[1];
      a0  = fmaf(m2vw[2], frcp(fmaf(wa.z, blo(u), 1.f)), a0);
      a0b = fmaf(m2vw[3], frcp(fmaf(wa.w, bhi(u), 1.f)), a0b);
      u = (unsigned)er[2];
      a0  = fmaf(m2vw[4], frcp(fmaf(wb.x, blo(u), 1.f)), a0);
      a0b = fmaf(m2vw[5], frcp(fmaf(wb.y, bhi(u), 1.f)), a0b);
      u = (unsigned)er[3];
      a0  = fmaf(m2vw[6], frcp(fmaf(wb.z, blo(u), 1.f)), a0);
      a0b = fmaf(m2vw[7], frcp(fmaf(wb.w, bhi(u), 1.f)), a0b);
      u = (unsigned)er[4];
      a1  = fmaf(m2vw[0], frcp(fmaf(wa.x, blo(u), 1.f)), a1);
      a1b = fmaf(m2vw[1], frcp(fmaf(wa.y, bhi(u), 1.f)), a1b);
      u = (unsigned)er[5];
      a1  = fmaf(m2vw[2], frcp(fmaf(wa.z, blo(u), 1.f)), a1);
      a1b = fmaf(m2vw[3], frcp(fmaf(wa.w, bhi(u), 1.f)), a1b);
      u = (unsigned)er[6];
      a1  = fmaf(m2vw[4], frcp(fmaf(wb.x, blo(u), 1.f)), a1);
      a1b = fmaf(m2vw[5], frcp(fmaf(wb.y, bhi(u), 1.f)), a1b);
      u = (unsigned)er[7];
      a1  = fmaf(m2vw[6], frcp(fmaf(wb.z, blo(u), 1.f)), a1);
      a1b = fmaf(m2vw[7], frcp(fmaf(wb.w, bhi(u), 1.f)), a1b);
      float s0 = sum16(a0 + a0b);
      float s1 = sum16(a1 + a1b);
      const float e0 = fexp2(L2E * s0);
      const float e1 = fexp2(L2E * s1);
      if (s_l == 0) {
        part64[4 * wid + dp] = e0 + e1;               // group d-pair partial
        xpk[wid][dp] = pkf16(e0 * xv.x, e1 * xv.y);   // GEMV input (half2)
        *reinterpret_cast<float2*>(&xh[t][d0]) =      // e*x f32 (x_hat deferred)
            make_float2(e0 * xv.x, e1 * xv.y);
      }
    }
    __syncthreads();

    // ---- D+E: sum64(part) hidden under gates GEMV; LSTM cell
    {
      float tot = part64[lane];
      tot = sum16(tot);
      tot += __int_as_float(__builtin_amdgcn_ds_swizzle(__float_as_int(tot), 0x401F)); // xor16
      tot += __shfl_xor(tot, 32);
      const float rs = frcp(tot);
      const int4 xq = *reinterpret_cast<const int4*>(&xpk[cD][0]);
      const __half2 x01 = uh((unsigned)xq.x), x23 = uh((unsigned)xq.y);
      const __half2 x45 = uh((unsigned)xq.z), x67 = uh((unsigned)xq.w);
      const __half2 h01 = uh((unsigned)hh.x), h23 = uh((unsigned)hh.y);
      float ac[4];
#pragma unroll
      for (int g = 0; g < 4; ++g) {
        __half2 ax = uh(0u), ah = uh(0u);
        ax = __hfma2(x01, uh(wx2[4*g]),   ax);
        ah = __hfma2(h01, uh(wh2[2*g]),   ah);
        ax = __hfma2(x23, uh(wx2[4*g+1]), ax);
        ah = __hfma2(h23, uh(wh2[2*g+1]), ah);
        ax = __hfma2(x45, uh(wx2[4*g+2]), ax);
        ax = __hfma2(x67, uh(wx2[4*g+3]), ax);
        const float fx = __low2float(ax) + __high2float(ax);
        const float fh = __low2float(ah) + __high2float(ah);
        ac[g] = sum16(fmaf(fx, rs, fh));
      }
      const float gi = ac[0] + b4[0];
      const float gf = ac[1] + b4[1];
      const float gG = ac[2] + b4[2];
      const float go = ac[3] + b4[3];
      const float si = frcp(1.f + fexp2(-L2E * gi));
      const float sf = frcp(1.f + fexp2(-L2E * gf));
      const float tg = 1.f - 2.f * frcp(1.f + fexp2(C2 * gG));
      const float cn = fmaf(sf, c_old, si * tg);
      const float so = frcp(1.f + fexp2(-L2E * go));
      const float tc = 1.f - 2.f * frcp(1.f + fexp2(C2 * cn));
      const float hn = so * tc;
      if (cD == 0) {
        __half* Hb = reinterpret_cast<__half*>(&hcpk[p ^ 1][0][0]);
        Hb[(kD >> 4) * 24 + (kD & 15)]       = __float2half_rn(hn);
        Hb[(4 + (kD >> 4)) * 24 + (kD & 15)] = __float2half_rn(cn);
        cq[p ^ 1][wid][kk] = cn;
        hbuf[t][kD] = hn;
      }
      if (tid == 0) rsb[t] = rs;
    }
    __syncthreads();
    p ^= 1;
  }

  // ---------------- bulk flush of outputs -----------------------------------
#pragma unroll
  for (int i = 0; i < 4; ++i) {
    const int f = i * 1024 + tid;
    const int t = f >> 5, c = (f & 31) << 2;
    float4 v = *reinterpret_cast<const float4*>(&xh[t][c]);
    const float rs = rsb[t];
    v.x *= rs; v.y *= rs; v.z *= rs; v.w *= rs;
    *reinterpret_cast<float4*>(out + b * (NT * ND) + t * ND + c) = v;
  }
  float* out2 = out + NB * (NT * ND) + b * (NT * NH);
#pragma unroll
  for (int i = 0; i < 2; ++i) {
    const int f = i * 1024 + tid;
    const int t = f >> 4, c = (f & 15) << 2;
    *reinterpret_cast<float4*>(out2 + t * NH + c) =
        *reinterpret_cast<const float4*>(&hbuf[t][c]);
  }
}

extern "C" void kernel_launch(void* const* d_in, const int* in_sizes, int n_in,
                              void* d_out, int out_size, void* d_ws, size_t ws_size,
                              hipStream_t stream) {
  const float* x    = (const float*)d_in[0];
  const float* Wehs = (const float*)d_in[1];
  const float* behs = (const float*)d_in[2];
  const float* Ue   = (const float*)d_in[3];
  const float* Ueb  = (const float*)d_in[4];
  const float* vew  = (const float*)d_in[5];
  // d_in[6] = v_e_b: constant shift before softmax -> no effect, unused.
  const float* Wih  = (const float*)d_in[7];
  const float* Whh  = (const float*)d_in[8];
  const float* bih  = (const float*)d_in[9];
  const float* bhh  = (const float*)d_in[10];
  float* out = (float*)d_out;

  darnn_enc<<<NB, NTH, 0, stream>>>(x, Wehs, behs, Ue, Ueb, vew, Wih, Whh, bih, bhh, out);
}

// Round 9
// 283.733 us; speedup vs baseline: 1.3667x; 1.0174x over previous
//
#include <hip/hip_runtime.h>
#include <hip/hip_bf16.h>
#include <hip/hip_fp16.h>

#define NB 128      // batch
#define NT 128      // Tm1
#define ND 128      // input size (drivers)
#define NH 64       // hidden
#define NTH 1024    // threads per block
#define ESTR 144    // Ebt row stride (ushorts)

typedef float f32x2 __attribute__((ext_vector_type(2)));

__device__ __forceinline__ float fexp2(float x) { return __builtin_amdgcn_exp2f(x); }
__device__ __forceinline__ float frcp (float x) { return __builtin_amdgcn_rcpf(x); }

template<int CTRL>
__device__ __forceinline__ float dppadd(float v) {
  return v + __int_as_float(__builtin_amdgcn_update_dpp(
      0, __float_as_int(v), CTRL, 0xF, 0xF, true));
}
__device__ __forceinline__ float sum16(float v) {
  v = dppadd<0xB1>(v);   // quad_perm [1,0,3,2]
  v = dppadd<0x4E>(v);   // quad_perm [2,3,0,1]
  v = dppadd<0x141>(v);  // row_half_mirror
  v = dppadd<0x140>(v);  // row_mirror
  return v;
}

// f32 -> bf16 bits, round-to-nearest-even
__device__ __forceinline__ unsigned short f2bf(float f) {
  unsigned u = __float_as_uint(f);
  u += 0x7fffu + ((u >> 16) & 1u);
  return (unsigned short)(u >> 16);
}
__device__ __forceinline__ float blo(unsigned u) { return __uint_as_float(u << 16); }
__device__ __forceinline__ float bhi(unsigned u) { return __uint_as_float(u & 0xffff0000u); }

// u32 <-> __half2 bit casts
__device__ __forceinline__ __half2 uh(unsigned u) {
  union { unsigned u; __half2 h; } x; x.u = u; return x.h;
}
__device__ __forceinline__ unsigned hu(__half2 h) {
  union { unsigned u; __half2 h; } x; x.h = h; return x.u;
}
__device__ __forceinline__ unsigned pkf16(float lo, float hi) {
  return hu(__halves2half2(__float2half_rn(lo), __float2half_rn(hi)));
}

#define PIN(v) asm volatile("" : "+v"(v))

__global__ __launch_bounds__(NTH)
__attribute__((amdgpu_waves_per_eu(4, 4)))
void darnn_enc(
    const float* __restrict__ x,     // [B][T1][D]
    const float* __restrict__ Wehs,  // [T1][2H]
    const float* __restrict__ behs,  // [T1]
    const float* __restrict__ Ue,    // [T1][T1]
    const float* __restrict__ Ueb,   // [T1]
    const float* __restrict__ vew,   // [T1]
    const float* __restrict__ Wih,   // [4H][D]
    const float* __restrict__ Whh,   // [4H][H]
    const float* __restrict__ bih,   // [256]
    const float* __restrict__ bhh,   // [256]
    float* __restrict__ out)
{
  constexpr float C2  = 2.88539008177792681f;  // 2*log2(e)
  constexpr float L2E = 1.44269504088896340f;  // log2(e)

  __shared__ __align__(16) float          xh[NT][ND];     // 64K: x, overwritten by e*x
  __shared__ __align__(16) unsigned short Ebt[ND][ESTR];  // 36.9K: E bf16 (prologue)
  __shared__ __align__(16) float          hbuf[NT][NH];   // 32K: h outputs (prologue: UeTc)
  __shared__ __align__(16) unsigned       hcpk[2][8][12]; // [h|c] as half2, dbuf
  __shared__ __align__(16) float          cq[2][16][6];   // c f32 (cell state), dbuf
  __shared__ __align__(16) float          wvm[16][12];    // w_s = exp(2*we), 8/row
  __shared__ __align__(16) unsigned       xpk[16][12];    // e*x as half2, 8 vals/row
  __shared__ __align__(16) float          part64[64];     // per-d-pair partial sums of e
  __shared__ __align__(16) float          rsb[NT];        // 1/sum(e) per step

  const int b    = blockIdx.x;
  const int tid  = threadIdx.x;
  const int lane = tid & 63;
  const int wid  = tid >> 6;
  const float* xb = x + b * (NT * ND);

  // ---------------- stage x into LDS ---------------------------------------
#pragma unroll
  for (int i = 0; i < 4; ++i) {
    const int f = i * 1024 + tid;
    const int t = f >> 5, c = (f & 31) << 2;
    *reinterpret_cast<float4*>(&xh[t][c]) =
        *reinterpret_cast<const float4*>(xb + t * ND + c);
  }
  float (*UeTc)[33] = reinterpret_cast<float(*)[33]>(&hbuf[0][0]);
  __syncthreads();

  // ---------------- Prologue: E[d][s] = exp(2*(x_perm @ Ue^T + Ueb)) --------
  {
    const int dq = tid & 31;
    const int sg = tid >> 5;
    float acc[16];
#pragma unroll
    for (int i = 0; i < 16; ++i) acc[i] = 0.f;
    for (int c = 0; c < 4; ++c) {
      {
        const int ss = 32 * c + sg;
        const int t4 = dq * 4;
        const float4 u4 = *reinterpret_cast<const float4*>(Ue + ss * NT + t4);
        UeTc[t4 + 0][sg] = u4.x;
        UeTc[t4 + 1][sg] = u4.y;
        UeTc[t4 + 2][sg] = u4.z;
        UeTc[t4 + 3][sg] = u4.w;
      }
      __syncthreads();
#pragma unroll 4
      for (int t = 0; t < NT; ++t) {
        const float4 xv = *reinterpret_cast<const float4*>(&xh[t][4 * dq]);
        const float u = UeTc[t][sg];
        acc[4*c+0] = fmaf(xv.x, u, acc[4*c+0]);
        acc[4*c+1] = fmaf(xv.y, u, acc[4*c+1]);
        acc[4*c+2] = fmaf(xv.z, u, acc[4*c+2]);
        acc[4*c+3] = fmaf(xv.w, u, acc[4*c+3]);
      }
      __syncthreads();
    }
#pragma unroll
    for (int c = 0; c < 4; ++c) {
      const int ss = sg + 32 * c;
      const float ub = Ueb[ss];
#pragma unroll
      for (int di = 0; di < 4; ++di) {
        const float e = fexp2(C2 * (acc[4*c+di] + ub));
        Ebt[4*dq + di][ss] = f2bf(e);
      }
    }
  }
  __syncthreads();   // Ebt complete before register loads

  // zero h/c state (both parities)
  if (tid < 192) (&hcpk[0][0][0])[tid] = 0u;          // half2(0,0)
  if (tid < 192) (&cq[0][0][0])[tid] = 0.f;

  // ---------------- persistent per-thread registers -------------------------
  // phase A: 8 threads per s; 16 hc-inputs per thread as 8 half2
  const int s_a = tid >> 3, r_a = tid & 7;
  unsigned wehs_p[8];
#pragma unroll
  for (int i = 0; i < 4; ++i) {
    const float4 v4 = *reinterpret_cast<const float4*>(Wehs + s_a * 128 + r_a * 16 + 4 * i);
    wehs_p[2*i]   = pkf16(v4.x, v4.y);
    wehs_p[2*i+1] = pkf16(v4.z, v4.w);
  }
  float behs_r = behs[s_a];

  // phase B: lane = s_l + 16*dp; d0 = 8*wid + 2*dp
  const int s_l = lane & 15;
  const int dp  = lane >> 4;
  const int d0  = 8 * wid + 2 * dp;
  f32x2 mv[4];
  {
    const float4 va = *reinterpret_cast<const float4*>(vew + 8 * s_l);
    const float4 vb = *reinterpret_cast<const float4*>(vew + 8 * s_l + 4);
    mv[0] = (f32x2){-2.f * va.x, -2.f * va.y};
    mv[1] = (f32x2){-2.f * va.z, -2.f * va.w};
    mv[2] = (f32x2){-2.f * vb.x, -2.f * vb.y};
    mv[3] = (f32x2){-2.f * vb.z, -2.f * vb.w};
  }
  // E fragments as f32 pairs (time-invariant, pre-unpacked from bf16)
  f32x2 er2[8];
  {
    const int4 ea = *reinterpret_cast<const int4*>(&Ebt[d0][8 * s_l]);
    const int4 eb = *reinterpret_cast<const int4*>(&Ebt[d0 + 1][8 * s_l]);
    er2[0] = (f32x2){blo((unsigned)ea.x), bhi((unsigned)ea.x)};
    er2[1] = (f32x2){blo((unsigned)ea.y), bhi((unsigned)ea.y)};
    er2[2] = (f32x2){blo((unsigned)ea.z), bhi((unsigned)ea.z)};
    er2[3] = (f32x2){blo((unsigned)ea.w), bhi((unsigned)ea.w)};
    er2[4] = (f32x2){blo((unsigned)eb.x), bhi((unsigned)eb.x)};
    er2[5] = (f32x2){blo((unsigned)eb.y), bhi((unsigned)eb.y)};
    er2[6] = (f32x2){blo((unsigned)eb.z), bhi((unsigned)eb.z)};
    er2[7] = (f32x2){blo((unsigned)eb.w), bhi((unsigned)eb.w)};
  }

  // phase D+E: lane = 16*kk + cD; unit kD = 4*wid + kk; 4 gates per lane
  const int kk = lane >> 4, cD = lane & 15;
  const int kD = 4 * wid + kk;
  unsigned wx2[16], wh2[8];   // half2-packed gate weights
  float b4[4];
#pragma unroll
  for (int g = 0; g < 4; ++g) {
    const int j = 64 * g + kD;
    const float4 u0 = *reinterpret_cast<const float4*>(Wih + j * 128 + 8 * cD);
    const float4 u1 = *reinterpret_cast<const float4*>(Wih + j * 128 + 8 * cD + 4);
    wx2[4*g]   = pkf16(u0.x, u0.y);
    wx2[4*g+1] = pkf16(u0.z, u0.w);
    wx2[4*g+2] = pkf16(u1.x, u1.y);
    wx2[4*g+3] = pkf16(u1.z, u1.w);
    const float4 u2 = *reinterpret_cast<const float4*>(Whh + j * 64 + 4 * cD);
    wh2[2*g]   = pkf16(u2.x, u2.y);
    wh2[2*g+1] = pkf16(u2.z, u2.w);
    b4[g] = bih[j] + bhh[j];
  }

#pragma unroll
  for (int i = 0; i < 8; ++i) PIN(wehs_p[i]);
#pragma unroll
  for (int i = 0; i < 8; ++i) PIN(er2[i]);
#pragma unroll
  for (int i = 0; i < 4; ++i) PIN(mv[i]);
#pragma unroll
  for (int i = 0; i < 16; ++i) PIN(wx2[i]);
#pragma unroll
  for (int i = 0; i < 8; ++i) PIN(wh2[i]);
#pragma unroll
  for (int g = 0; g < 4; ++g) PIN(b4[g]);
  PIN(behs_r);

  __syncthreads();

  // ---------------- main recurrence: 3 barriers/step, no global mem ---------
  int p = 0;
  for (int t = 0; t < NT; ++t) {
    // prefetch x_t pair for B's writers (row t untouched until B writes it)
    const float2 xv = *reinterpret_cast<const float2*>(&xh[t][d0]);

    // ---- A: we[s] = behs[s] + hc . Wehs[s,:];  w_s = exp(2*we)  (pk f16)
    {
      const int4 q0 = *reinterpret_cast<const int4*>(&hcpk[p][r_a][0]);
      const int4 q1 = *reinterpret_cast<const int4*>(&hcpk[p][r_a][4]);
      __half2 ac0 = uh(0u), ac1 = uh(0u);
      ac0 = __hfma2(uh((unsigned)q0.x), uh(wehs_p[0]), ac0);
      ac1 = __hfma2(uh((unsigned)q0.y), uh(wehs_p[1]), ac1);
      ac0 = __hfma2(uh((unsigned)q0.z), uh(wehs_p[2]), ac0);
      ac1 = __hfma2(uh((unsigned)q0.w), uh(wehs_p[3]), ac1);
      ac0 = __hfma2(uh((unsigned)q1.x), uh(wehs_p[4]), ac0);
      ac1 = __hfma2(uh((unsigned)q1.y), uh(wehs_p[5]), ac1);
      ac0 = __hfma2(uh((unsigned)q1.z), uh(wehs_p[6]), ac0);
      ac1 = __hfma2(uh((unsigned)q1.w), uh(wehs_p[7]), ac1);
      float a0 = (__low2float(ac0) + __high2float(ac0)) +
                 (__low2float(ac1) + __high2float(ac1));
      a0 = dppadd<0xB1>(a0);
      a0 = dppadd<0x4E>(a0);
      a0 = dppadd<0x141>(a0);
      if (r_a == 0) wvm[s_a >> 3][s_a & 7] = fexp2(C2 * (a0 + behs_r));
    }
    __syncthreads();

    // ---- B': e[d] = exp(v[d]); packed-f32 core; writers stage e*x; partials
    int2 hh; float c_old;
    {
      const float4 wa = *reinterpret_cast<const float4*>(&wvm[s_l][0]);
      const float4 wb = *reinterpret_cast<const float4*>(&wvm[s_l][4]);
      // prefetch D's inputs (stable: written by D of step t-1)
      hh    = *reinterpret_cast<const int2*>(&hcpk[p][cD >> 2][2 * (cD & 3)]);
      c_old = cq[p][wid][kk];
      const f32x2 one2 = {1.f, 1.f};
      const f32x2 w01 = {wa.x, wa.y}, w23 = {wa.z, wa.w};
      const f32x2 w45 = {wb.x, wb.y}, w67 = {wb.z, wb.w};
      f32x2 ac0 = {0.f, 0.f}, ac0b = {0.f, 0.f};
      f32x2 ac1 = {0.f, 0.f}, ac1b = {0.f, 0.f};
#define BSTEP(W, E, M, ACC) do {                                   \
        f32x2 q_ = __builtin_elementwise_fma(W, E, one2);          \
        f32x2 r_; r_.x = frcp(q_.x); r_.y = frcp(q_.y);            \
        ACC = __builtin_elementwise_fma(M, r_, ACC);               \
      } while (0)
      BSTEP(w01, er2[0], mv[0], ac0);
      BSTEP(w23, er2[1], mv[1], ac0b);
      BSTEP(w45, er2[2], mv[2], ac0);
      BSTEP(w67, er2[3], mv[3], ac0b);
      BSTEP(w01, er2[4], mv[0], ac1);
      BSTEP(w23, er2[5], mv[1], ac1b);
      BSTEP(w45, er2[6], mv[2], ac1);
      BSTEP(w67, er2[7], mv[3], ac1b);
#undef BSTEP
      const f32x2 sv0 = ac0 + ac0b;
      const f32x2 sv1 = ac1 + ac1b;
      float s0 = sum16(sv0.x + sv0.y);
      float s1 = sum16(sv1.x + sv1.y);
      const float e0 = fexp2(L2E * s0);
      const float e1 = fexp2(L2E * s1);
      if (s_l == 0) {
        part64[4 * wid + dp] = e0 + e1;               // group d-pair partial
        xpk[wid][dp] = pkf16(e0 * xv.x, e1 * xv.y);   // GEMV input (half2)
        *reinterpret_cast<float2*>(&xh[t][d0]) =      // e*x f32 (x_hat deferred)
            make_float2(e0 * xv.x, e1 * xv.y);
      }
    }
    __syncthreads();

    // ---- D+E: sum64(part) hidden under gates GEMV; LSTM cell
    {
      float tot = part64[lane];
      tot = sum16(tot);
      tot += __int_as_float(__builtin_amdgcn_ds_swizzle(__float_as_int(tot), 0x401F)); // xor16
      tot += __shfl_xor(tot, 32);
      const float rs = frcp(tot);
      const int4 xq = *reinterpret_cast<const int4*>(&xpk[cD][0]);
      const __half2 x01 = uh((unsigned)xq.x), x23 = uh((unsigned)xq.y);
      const __half2 x45 = uh((unsigned)xq.z), x67 = uh((unsigned)xq.w);
      const __half2 h01 = uh((unsigned)hh.x), h23 = uh((unsigned)hh.y);
      float ac[4];
#pragma unroll
      for (int g = 0; g < 4; ++g) {
        __half2 ax = uh(0u), ah = uh(0u);
        ax = __hfma2(x01, uh(wx2[4*g]),   ax);
        ah = __hfma2(h01, uh(wh2[2*g]),   ah);
        ax = __hfma2(x23, uh(wx2[4*g+1]), ax);
        ah = __hfma2(h23, uh(wh2[2*g+1]), ah);
        ax = __hfma2(x45, uh(wx2[4*g+2]), ax);
        ax = __hfma2(x67, uh(wx2[4*g+3]), ax);
        const float fx = __low2float(ax) + __high2float(ax);
        const float fh = __low2float(ah) + __high2float(ah);
        ac[g] = sum16(fmaf(fx, rs, fh));
      }
      const float gi = ac[0] + b4[0];
      const float gf = ac[1] + b4[1];
      const float gG = ac[2] + b4[2];
      const float go = ac[3] + b4[3];
      const float si = frcp(1.f + fexp2(-L2E * gi));
      const float sf = frcp(1.f + fexp2(-L2E * gf));
      const float tg = 1.f - 2.f * frcp(1.f + fexp2(C2 * gG));
      const float cn = fmaf(sf, c_old, si * tg);
      const float so = frcp(1.f + fexp2(-L2E * go));
      const float tc = 1.f - 2.f * frcp(1.f + fexp2(C2 * cn));
      const float hn = so * tc;
      if (cD == 0) {
        __half* Hb = reinterpret_cast<__half*>(&hcpk[p ^ 1][0][0]);
        Hb[(kD >> 4) * 24 + (kD & 15)]       = __float2half_rn(hn);
        Hb[(4 + (kD >> 4)) * 24 + (kD & 15)] = __float2half_rn(cn);
        cq[p ^ 1][wid][kk] = cn;
        hbuf[t][kD] = hn;
      }
      if (tid == 0) rsb[t] = rs;
    }
    __syncthreads();
    p ^= 1;
  }

  // ---------------- bulk flush of outputs -----------------------------------
#pragma unroll
  for (int i = 0; i < 4; ++i) {
    const int f = i * 1024 + tid;
    const int t = f >> 5, c = (f & 31) << 2;
    float4 v = *reinterpret_cast<const float4*>(&xh[t][c]);
    const float rs = rsb[t];
    v.x *= rs; v.y *= rs; v.z *= rs; v.w *= rs;
    *reinterpret_cast<float4*>(out + b * (NT * ND) + t * ND + c) = v;
  }
  float* out2 = out + NB * (NT * ND) + b * (NT * NH);
#pragma unroll
  for (int i = 0; i < 2; ++i) {
    const int f = i * 1024 + tid;
    const int t = f >> 4, c = (f & 15) << 2;
    *reinterpret_cast<float4*>(out2 + t * NH + c) =
        *reinterpret_cast<const float4*>(&hbuf[t][c]);
  }
}

extern "C" void kernel_launch(void* const* d_in, const int* in_sizes, int n_in,
                              void* d_out, int out_size, void* d_ws, size_t ws_size,
                              hipStream_t stream) {
  const float* x    = (const float*)d_in[0];
  const float* Wehs = (const float*)d_in[1];
  const float* behs = (const float*)d_in[2];
  const float* Ue   = (const float*)d_in[3];
  const float* Ueb  = (const float*)d_in[4];
  const float* vew  = (const float*)d_in[5];
  // d_in[6] = v_e_b: constant shift before softmax -> no effect, unused.
  const float* Wih  = (const float*)d_in[7];
  const float* Whh  = (const float*)d_in[8];
  const float* bih  = (const float*)d_in[9];
  const float* bhh  = (const float*)d_in[10];
  float* out = (float*)d_out;

  darnn_enc<<<NB, NTH, 0, stream>>>(x, Wehs, behs, Ue, Ueb, vew, Wih, Whh, bih, bhh, out);
}

// Round 10
// 270.775 us; speedup vs baseline: 1.4321x; 1.0479x over previous
//
#include <hip/hip_runtime.h>
#include <hip/hip_bf16.h>
#include <hip/hip_fp16.h>

#define NB 128      // batch
#define NT 128      // Tm1
#define ND 128      // input size (drivers)
#define NH 64       // hidden
#define NTH 1024    // threads per block
#define ESTR 144    // Ebt row stride (ushorts)

typedef float f32x2 __attribute__((ext_vector_type(2)));
typedef _Float16 f16x2 __attribute__((ext_vector_type(2)));

__device__ __forceinline__ float fexp2(float x) { return __builtin_amdgcn_exp2f(x); }
__device__ __forceinline__ float frcp (float x) { return __builtin_amdgcn_rcpf(x); }

template<int CTRL>
__device__ __forceinline__ float dppadd(float v) {
  return v + __int_as_float(__builtin_amdgcn_update_dpp(
      0, __float_as_int(v), CTRL, 0xF, 0xF, true));
}
__device__ __forceinline__ float sum16(float v) {
  v = dppadd<0xB1>(v);   // quad_perm [1,0,3,2]
  v = dppadd<0x4E>(v);   // quad_perm [2,3,0,1]
  v = dppadd<0x141>(v);  // row_half_mirror
  v = dppadd<0x140>(v);  // row_mirror
  return v;
}

// f32 -> bf16 bits, round-to-nearest-even
__device__ __forceinline__ unsigned short f2bf(float f) {
  unsigned u = __float_as_uint(f);
  u += 0x7fffu + ((u >> 16) & 1u);
  return (unsigned short)(u >> 16);
}
__device__ __forceinline__ float blo(unsigned u) { return __uint_as_float(u << 16); }
__device__ __forceinline__ float bhi(unsigned u) { return __uint_as_float(u & 0xffff0000u); }

// u32 <-> __half2 bit casts
__device__ __forceinline__ __half2 uh(unsigned u) {
  union { unsigned u; __half2 h; } x; x.u = u; return x.h;
}
__device__ __forceinline__ unsigned hu(__half2 h) {
  union { unsigned u; __half2 h; } x; x.h = h; return x.u;
}
__device__ __forceinline__ f16x2 uh2(unsigned u) {
  union { unsigned u; f16x2 h; } x; x.u = u; return x.h;
}
__device__ __forceinline__ unsigned pkf16(float lo, float hi) {
  return hu(__halves2half2(__float2half_rn(lo), __float2half_rn(hi)));
}

// 2-way f16 dot with f32 accumulate: v_dot2_f32_f16 (no unpack glue)
__device__ __forceinline__ float dot2(unsigned a, unsigned b, float c) {
#if __has_builtin(__builtin_amdgcn_fdot2)
  return __builtin_amdgcn_fdot2(uh2(a), uh2(b), c, false);
#else
  const __half2 p = __hmul2(uh(a), uh(b));
  return c + __low2float(p) + __high2float(p);
#endif
}

#define PIN(v) asm volatile("" : "+v"(v))

__global__ __launch_bounds__(NTH)
__attribute__((amdgpu_waves_per_eu(4, 4)))
void darnn_enc(
    const float* __restrict__ x,     // [B][T1][D]
    const float* __restrict__ Wehs,  // [T1][2H]
    const float* __restrict__ behs,  // [T1]
    const float* __restrict__ Ue,    // [T1][T1]
    const float* __restrict__ Ueb,   // [T1]
    const float* __restrict__ vew,   // [T1]
    const float* __restrict__ Wih,   // [4H][D]
    const float* __restrict__ Whh,   // [4H][H]
    const float* __restrict__ bih,   // [256]
    const float* __restrict__ bhh,   // [256]
    float* __restrict__ out)
{
  constexpr float C2  = 2.88539008177792681f;  // 2*log2(e)
  constexpr float L2E = 1.44269504088896340f;  // log2(e)

  __shared__ __align__(16) float          xh[NT][ND];     // 64K: x, overwritten by e*x
  __shared__ __align__(16) unsigned short Ebt[ND][ESTR];  // 36.9K: E bf16 (prologue)
  __shared__ __align__(16) float          hbuf[NT][NH];   // 32K: h outputs (prologue: UeTc)
  __shared__ __align__(16) unsigned       hcpk[2][8][12]; // [h|c] as half2, dbuf
  __shared__ __align__(16) float          cq[2][16][6];   // c f32 (cell state), dbuf
  __shared__ __align__(16) float          wvm[16][12];    // w_s = exp(2*we), 8/row
  __shared__ __align__(16) unsigned       xpk[16][12];    // e*x as half2, 8 vals/row
  __shared__ __align__(16) float          part64[64];     // per-d-pair partial sums of e
  __shared__ __align__(16) float          rsb[NT];        // 1/sum(e) per step

  const int b    = blockIdx.x;
  const int tid  = threadIdx.x;
  const int lane = tid & 63;
  const int wid  = tid >> 6;
  const float* xb = x + b * (NT * ND);

  // ---------------- stage x into LDS ---------------------------------------
#pragma unroll
  for (int i = 0; i < 4; ++i) {
    const int f = i * 1024 + tid;
    const int t = f >> 5, c = (f & 31) << 2;
    *reinterpret_cast<float4*>(&xh[t][c]) =
        *reinterpret_cast<const float4*>(xb + t * ND + c);
  }
  float (*UeTc)[33] = reinterpret_cast<float(*)[33]>(&hbuf[0][0]);
  __syncthreads();

  // ---------------- Prologue: E[d][s] = exp(2*(x_perm @ Ue^T + Ueb)) --------
  {
    const int dq = tid & 31;
    const int sg = tid >> 5;
    float acc[16];
#pragma unroll
    for (int i = 0; i < 16; ++i) acc[i] = 0.f;
    for (int c = 0; c < 4; ++c) {
      {
        const int ss = 32 * c + sg;
        const int t4 = dq * 4;
        const float4 u4 = *reinterpret_cast<const float4*>(Ue + ss * NT + t4);
        UeTc[t4 + 0][sg] = u4.x;
        UeTc[t4 + 1][sg] = u4.y;
        UeTc[t4 + 2][sg] = u4.z;
        UeTc[t4 + 3][sg] = u4.w;
      }
      __syncthreads();
#pragma unroll 4
      for (int t = 0; t < NT; ++t) {
        const float4 xv = *reinterpret_cast<const float4*>(&xh[t][4 * dq]);
        const float u = UeTc[t][sg];
        acc[4*c+0] = fmaf(xv.x, u, acc[4*c+0]);
        acc[4*c+1] = fmaf(xv.y, u, acc[4*c+1]);
        acc[4*c+2] = fmaf(xv.z, u, acc[4*c+2]);
        acc[4*c+3] = fmaf(xv.w, u, acc[4*c+3]);
      }
      __syncthreads();
    }
#pragma unroll
    for (int c = 0; c < 4; ++c) {
      const int ss = sg + 32 * c;
      const float ub = Ueb[ss];
#pragma unroll
      for (int di = 0; di < 4; ++di) {
        const float e = fexp2(C2 * (acc[4*c+di] + ub));
        Ebt[4*dq + di][ss] = f2bf(e);
      }
    }
  }
  __syncthreads();   // Ebt complete before register loads

  // zero h/c state (both parities)
  if (tid < 192) (&hcpk[0][0][0])[tid] = 0u;          // half2(0,0)
  if (tid < 192) (&cq[0][0][0])[tid] = 0.f;

  // ---------------- persistent per-thread registers -------------------------
  // phase A: 8 threads per s; 16 hc-inputs per thread as 8 half2
  const int s_a = tid >> 3, r_a = tid & 7;
  unsigned wehs_p[8];
#pragma unroll
  for (int i = 0; i < 4; ++i) {
    const float4 v4 = *reinterpret_cast<const float4*>(Wehs + s_a * 128 + r_a * 16 + 4 * i);
    wehs_p[2*i]   = pkf16(v4.x, v4.y);
    wehs_p[2*i+1] = pkf16(v4.z, v4.w);
  }
  float behs_r = behs[s_a];

  // phase B: lane = s_l + 16*dp; d0 = 8*wid + 2*dp
  const int s_l = lane & 15;
  const int dp  = lane >> 4;
  const int d0  = 8 * wid + 2 * dp;
  f32x2 mv[4];
  {
    const float4 va = *reinterpret_cast<const float4*>(vew + 8 * s_l);
    const float4 vb = *reinterpret_cast<const float4*>(vew + 8 * s_l + 4);
    mv[0] = (f32x2){-2.f * va.x, -2.f * va.y};
    mv[1] = (f32x2){-2.f * va.z, -2.f * va.w};
    mv[2] = (f32x2){-2.f * vb.x, -2.f * vb.y};
    mv[3] = (f32x2){-2.f * vb.z, -2.f * vb.w};
  }
  // E fragments as f32 pairs (time-invariant, pre-unpacked from bf16)
  f32x2 er2[8];
  {
    const int4 ea = *reinterpret_cast<const int4*>(&Ebt[d0][8 * s_l]);
    const int4 eb = *reinterpret_cast<const int4*>(&Ebt[d0 + 1][8 * s_l]);
    er2[0] = (f32x2){blo((unsigned)ea.x), bhi((unsigned)ea.x)};
    er2[1] = (f32x2){blo((unsigned)ea.y), bhi((unsigned)ea.y)};
    er2[2] = (f32x2){blo((unsigned)ea.z), bhi((unsigned)ea.z)};
    er2[3] = (f32x2){blo((unsigned)ea.w), bhi((unsigned)ea.w)};
    er2[4] = (f32x2){blo((unsigned)eb.x), bhi((unsigned)eb.x)};
    er2[5] = (f32x2){blo((unsigned)eb.y), bhi((unsigned)eb.y)};
    er2[6] = (f32x2){blo((unsigned)eb.z), bhi((unsigned)eb.z)};
    er2[7] = (f32x2){blo((unsigned)eb.w), bhi((unsigned)eb.w)};
  }

  // phase D+E: lane = 16*kk + cD; unit kD = 4*wid + kk; 4 gates per lane
  const int kk = lane >> 4, cD = lane & 15;
  const int kD = 4 * wid + kk;
  unsigned wx2[16], wh2[8];   // half2-packed gate weights
  float b4[4];
#pragma unroll
  for (int g = 0; g < 4; ++g) {
    const int j = 64 * g + kD;
    const float4 u0 = *reinterpret_cast<const float4*>(Wih + j * 128 + 8 * cD);
    const float4 u1 = *reinterpret_cast<const float4*>(Wih + j * 128 + 8 * cD + 4);
    wx2[4*g]   = pkf16(u0.x, u0.y);
    wx2[4*g+1] = pkf16(u0.z, u0.w);
    wx2[4*g+2] = pkf16(u1.x, u1.y);
    wx2[4*g+3] = pkf16(u1.z, u1.w);
    const float4 u2 = *reinterpret_cast<const float4*>(Whh + j * 64 + 4 * cD);
    wh2[2*g]   = pkf16(u2.x, u2.y);
    wh2[2*g+1] = pkf16(u2.z, u2.w);
    b4[g] = bih[j] + bhh[j];
  }

#pragma unroll
  for (int i = 0; i < 8; ++i) PIN(wehs_p[i]);
#pragma unroll
  for (int i = 0; i < 8; ++i) PIN(er2[i]);
#pragma unroll
  for (int i = 0; i < 4; ++i) PIN(mv[i]);
#pragma unroll
  for (int i = 0; i < 16; ++i) PIN(wx2[i]);
#pragma unroll
  for (int i = 0; i < 8; ++i) PIN(wh2[i]);
#pragma unroll
  for (int g = 0; g < 4; ++g) PIN(b4[g]);
  PIN(behs_r);

  __syncthreads();

  // ---------------- main recurrence: 3 barriers/step, no global mem ---------
  int p = 0;
  for (int t = 0; t < NT; ++t) {
    // prefetch x_t pair for B's writers (row t untouched until B writes it)
    const float2 xv = *reinterpret_cast<const float2*>(&xh[t][d0]);

    // ---- A: we[s] = behs[s] + hc . Wehs[s,:];  w_s = exp(2*we)  (dot2)
    {
      const int4 q0 = *reinterpret_cast<const int4*>(&hcpk[p][r_a][0]);
      const int4 q1 = *reinterpret_cast<const int4*>(&hcpk[p][r_a][4]);
      float a0 = 0.f, a1 = 0.f;
      a0 = dot2((unsigned)q0.x, wehs_p[0], a0);
      a1 = dot2((unsigned)q0.y, wehs_p[1], a1);
      a0 = dot2((unsigned)q0.z, wehs_p[2], a0);
      a1 = dot2((unsigned)q0.w, wehs_p[3], a1);
      a0 = dot2((unsigned)q1.x, wehs_p[4], a0);
      a1 = dot2((unsigned)q1.y, wehs_p[5], a1);
      a0 = dot2((unsigned)q1.z, wehs_p[6], a0);
      a1 = dot2((unsigned)q1.w, wehs_p[7], a1);
      float a = a0 + a1;
      a = dppadd<0xB1>(a);
      a = dppadd<0x4E>(a);
      a = dppadd<0x141>(a);
      if (r_a == 0) wvm[s_a >> 3][s_a & 7] = fexp2(C2 * (a + behs_r));
    }
    __syncthreads();

    // ---- B': e[d] = exp(v[d]); packed-f32 core; writers stage e*x; partials
    int2 hh; float c_old;
    {
      const float4 wa = *reinterpret_cast<const float4*>(&wvm[s_l][0]);
      const float4 wb = *reinterpret_cast<const float4*>(&wvm[s_l][4]);
      // prefetch D's inputs (stable: written by D of step t-1)
      hh    = *reinterpret_cast<const int2*>(&hcpk[p][cD >> 2][2 * (cD & 3)]);
      c_old = cq[p][wid][kk];
      const f32x2 one2 = {1.f, 1.f};
      const f32x2 w01 = {wa.x, wa.y}, w23 = {wa.z, wa.w};
      const f32x2 w45 = {wb.x, wb.y}, w67 = {wb.z, wb.w};
      f32x2 ac0 = {0.f, 0.f}, ac0b = {0.f, 0.f};
      f32x2 ac1 = {0.f, 0.f}, ac1b = {0.f, 0.f};
#define BSTEP(W, E, M, ACC) do {                                   \
        f32x2 q_ = __builtin_elementwise_fma(W, E, one2);          \
        f32x2 r_; r_.x = frcp(q_.x); r_.y = frcp(q_.y);            \
        ACC = __builtin_elementwise_fma(M, r_, ACC);               \
      } while (0)
      BSTEP(w01, er2[0], mv[0], ac0);
      BSTEP(w23, er2[1], mv[1], ac0b);
      BSTEP(w45, er2[2], mv[2], ac0);
      BSTEP(w67, er2[3], mv[3], ac0b);
      BSTEP(w01, er2[4], mv[0], ac1);
      BSTEP(w23, er2[5], mv[1], ac1b);
      BSTEP(w45, er2[6], mv[2], ac1);
      BSTEP(w67, er2[7], mv[3], ac1b);
#undef BSTEP
      const f32x2 sv0 = ac0 + ac0b;
      const f32x2 sv1 = ac1 + ac1b;
      float s0 = sum16(sv0.x + sv0.y);
      float s1 = sum16(sv1.x + sv1.y);
      const float e0 = fexp2(L2E * s0);
      const float e1 = fexp2(L2E * s1);
      if (s_l == 0) {
        part64[4 * wid + dp] = e0 + e1;               // group d-pair partial
        xpk[wid][dp] = pkf16(e0 * xv.x, e1 * xv.y);   // GEMV input (half2)
        *reinterpret_cast<float2*>(&xh[t][d0]) =      // e*x f32 (x_hat deferred)
            make_float2(e0 * xv.x, e1 * xv.y);
      }
    }
    __syncthreads();

    // ---- D+E: sum64(part) + gates via dot2 (f32 accum, rs pre-folded)
    {
      float tot = part64[lane];
      tot = sum16(tot);
      tot += __int_as_float(__builtin_amdgcn_ds_swizzle(__float_as_int(tot), 0x401F)); // xor16
      tot += __shfl_xor(tot, 32);
      const float rs = frcp(tot);
      const int4 xq = *reinterpret_cast<const int4*>(&xpk[cD][0]);
      // fold 1/sum(e) into the x inputs once (4 pk muls), then pure dot2 chains
      const __half2 rsh = __half2half2(__float2half_rn(rs));
      const unsigned xs0 = hu(__hmul2(uh((unsigned)xq.x), rsh));
      const unsigned xs1 = hu(__hmul2(uh((unsigned)xq.y), rsh));
      const unsigned xs2 = hu(__hmul2(uh((unsigned)xq.z), rsh));
      const unsigned xs3 = hu(__hmul2(uh((unsigned)xq.w), rsh));
      float ac[4];
#pragma unroll
      for (int g = 0; g < 4; ++g) {
        float s = 0.f;
        s = dot2(xs0, wx2[4*g],   s);
        s = dot2(xs1, wx2[4*g+1], s);
        s = dot2(xs2, wx2[4*g+2], s);
        s = dot2(xs3, wx2[4*g+3], s);
        s = dot2((unsigned)hh.x, wh2[2*g],   s);
        s = dot2((unsigned)hh.y, wh2[2*g+1], s);
        ac[g] = sum16(s);
      }
      const float gi = ac[0] + b4[0];
      const float gf = ac[1] + b4[1];
      const float gG = ac[2] + b4[2];
      const float go = ac[3] + b4[3];
      const float si = frcp(1.f + fexp2(-L2E * gi));
      const float sf = frcp(1.f + fexp2(-L2E * gf));
      const float tg = 1.f - 2.f * frcp(1.f + fexp2(C2 * gG));
      const float cn = fmaf(sf, c_old, si * tg);
      const float so = frcp(1.f + fexp2(-L2E * go));
      const float tc = 1.f - 2.f * frcp(1.f + fexp2(C2 * cn));
      const float hn = so * tc;
      if (cD == 0) {
        __half* Hb = reinterpret_cast<__half*>(&hcpk[p ^ 1][0][0]);
        Hb[(kD >> 4) * 24 + (kD & 15)]       = __float2half_rn(hn);
        Hb[(4 + (kD >> 4)) * 24 + (kD & 15)] = __float2half_rn(cn);
        cq[p ^ 1][wid][kk] = cn;
        hbuf[t][kD] = hn;
      }
      if (tid == 0) rsb[t] = rs;
    }
    __syncthreads();
    p ^= 1;
  }

  // ---------------- bulk flush of outputs -----------------------------------
#pragma unroll
  for (int i = 0; i < 4; ++i) {
    const int f = i * 1024 + tid;
    const int t = f >> 5, c = (f & 31) << 2;
    float4 v = *reinterpret_cast<const float4*>(&xh[t][c]);
    const float rs = rsb[t];
    v.x *= rs; v.y *= rs; v.z *= rs; v.w *= rs;
    *reinterpret_cast<float4*>(out + b * (NT * ND) + t * ND + c) = v;
  }
  float* out2 = out + NB * (NT * ND) + b * (NT * NH);
#pragma unroll
  for (int i = 0; i < 2; ++i) {
    const int f = i * 1024 + tid;
    const int t = f >> 4, c = (f & 15) << 2;
    *reinterpret_cast<float4*>(out2 + t * NH + c) =
        *reinterpret_cast<const float4*>(&hbuf[t][c]);
  }
}

extern "C" void kernel_launch(void* const* d_in, const int* in_sizes, int n_in,
                              void* d_out, int out_size, void* d_ws, size_t ws_size,
                              hipStream_t stream) {
  const float* x    = (const float*)d_in[0];
  const float* Wehs = (const float*)d_in[1];
  const float* behs = (const float*)d_in[2];
  const float* Ue   = (const float*)d_in[3];
  const float* Ueb  = (const float*)d_in[4];
  const float* vew  = (const float*)d_in[5];
  // d_in[6] = v_e_b: constant shift before softmax -> no effect, unused.
  const float* Wih  = (const float*)d_in[7];
  const float* Whh  = (const float*)d_in[8];
  const float* bih  = (const float*)d_in[9];
  const float* bhh  = (const float*)d_in[10];
  float* out = (float*)d_out;

  darnn_enc<<<NB, NTH, 0, stream>>>(x, Wehs, behs, Ue, Ueb, vew, Wih, Whh, bih, bhh, out);
}

// Round 11
// 265.029 us; speedup vs baseline: 1.4632x; 1.0217x over previous
//
#include <hip/hip_runtime.h>
#include <hip/hip_bf16.h>
#include <hip/hip_fp16.h>

#define NB 128      // batch
#define NT 128      // Tm1
#define ND 128      // input size (drivers)
#define NH 64       // hidden
#define NTH 1024    // threads per block
#define ESTR 144    // Ebt row stride (ushorts)

typedef float f32x2 __attribute__((ext_vector_type(2)));
typedef _Float16 f16x2 __attribute__((ext_vector_type(2)));

__device__ __forceinline__ float fexp2(float x) { return __builtin_amdgcn_exp2f(x); }
__device__ __forceinline__ float frcp (float x) { return __builtin_amdgcn_rcpf(x); }

template<int CTRL>
__device__ __forceinline__ float dppadd(float v) {
  return v + __int_as_float(__builtin_amdgcn_update_dpp(
      0, __float_as_int(v), CTRL, 0xF, 0xF, true));
}
__device__ __forceinline__ float sum16(float v) {
  v = dppadd<0xB1>(v);   // quad_perm [1,0,3,2]
  v = dppadd<0x4E>(v);   // quad_perm [2,3,0,1]
  v = dppadd<0x141>(v);  // row_half_mirror
  v = dppadd<0x140>(v);  // row_mirror
  return v;
}

// f32 -> bf16 bits, round-to-nearest-even
__device__ __forceinline__ unsigned short f2bf(float f) {
  unsigned u = __float_as_uint(f);
  u += 0x7fffu + ((u >> 16) & 1u);
  return (unsigned short)(u >> 16);
}
__device__ __forceinline__ float blo(unsigned u) { return __uint_as_float(u << 16); }
__device__ __forceinline__ float bhi(unsigned u) { return __uint_as_float(u & 0xffff0000u); }

// u32 <-> __half2 bit casts
__device__ __forceinline__ __half2 uh(unsigned u) {
  union { unsigned u; __half2 h; } x; x.u = u; return x.h;
}
__device__ __forceinline__ unsigned hu(__half2 h) {
  union { unsigned u; __half2 h; } x; x.h = h; return x.u;
}
__device__ __forceinline__ f16x2 uh2(unsigned u) {
  union { unsigned u; f16x2 h; } x; x.u = u; return x.h;
}
__device__ __forceinline__ unsigned pkf16(float lo, float hi) {
  return hu(__halves2half2(__float2half_rn(lo), __float2half_rn(hi)));
}

// 2-way f16 dot with f32 accumulate: v_dot2_f32_f16 (no unpack glue)
__device__ __forceinline__ float dot2(unsigned a, unsigned b, float c) {
#if __has_builtin(__builtin_amdgcn_fdot2)
  return __builtin_amdgcn_fdot2(uh2(a), uh2(b), c, false);
#else
  const __half2 p = __hmul2(uh(a), uh(b));
  return c + __low2float(p) + __high2float(p);
#endif
}

#define PIN(v) asm volatile("" : "+v"(v))

__global__ __launch_bounds__(NTH)
__attribute__((amdgpu_waves_per_eu(4, 4)))
void darnn_enc(
    const float* __restrict__ x,     // [B][T1][D]
    const float* __restrict__ Wehs,  // [T1][2H]
    const float* __restrict__ behs,  // [T1]
    const float* __restrict__ Ue,    // [T1][T1]
    const float* __restrict__ Ueb,   // [T1]
    const float* __restrict__ vew,   // [T1]
    const float* __restrict__ Wih,   // [4H][D]
    const float* __restrict__ Whh,   // [4H][H]
    const float* __restrict__ bih,   // [256]
    const float* __restrict__ bhh,   // [256]
    float* __restrict__ out)
{
  constexpr float C2  = 2.88539008177792681f;  // 2*log2(e)
  constexpr float L2E = 1.44269504088896340f;  // log2(e)

  __shared__ __align__(16) float          xh[NT][ND];     // 64K: x, overwritten by e*x
  __shared__ __align__(16) unsigned short Ebt[ND][ESTR];  // 36.9K: E bf16 (prologue)
  __shared__ __align__(16) float          hbuf[NT][NH];   // 32K: h outputs (prologue: UeTc)
  __shared__ __align__(16) unsigned       hcpk[2][8][12]; // [h|c] as half2, dbuf
  __shared__ __align__(16) float          cq[2][16][6];   // c f32 (cell state), dbuf
  __shared__ __align__(16) float          wvm[16][12];    // w_s (L2E-prefolded), 8/row
  __shared__ __align__(16) unsigned       xpk[16][12];    // e*x as half2, 8 vals/row
  __shared__ __align__(16) float          part64[64];     // per-d-pair partial sums of e
  __shared__ __align__(16) float          rsb[NT];        // 1/sum(e) per step

  const int b    = blockIdx.x;
  const int tid  = threadIdx.x;
  const int lane = tid & 63;
  const int wid  = tid >> 6;
  const float* xb = x + b * (NT * ND);

  // ---------------- stage x into LDS ---------------------------------------
#pragma unroll
  for (int i = 0; i < 4; ++i) {
    const int f = i * 1024 + tid;
    const int t = f >> 5, c = (f & 31) << 2;
    *reinterpret_cast<float4*>(&xh[t][c]) =
        *reinterpret_cast<const float4*>(xb + t * ND + c);
  }
  float (*UeTc)[33] = reinterpret_cast<float(*)[33]>(&hbuf[0][0]);
  __syncthreads();

  // ---------------- Prologue: E[d][s] = exp(2*(x_perm @ Ue^T + Ueb)) --------
  {
    const int dq = tid & 31;
    const int sg = tid >> 5;
    float acc[16];
#pragma unroll
    for (int i = 0; i < 16; ++i) acc[i] = 0.f;
    for (int c = 0; c < 4; ++c) {
      {
        const int ss = 32 * c + sg;
        const int t4 = dq * 4;
        const float4 u4 = *reinterpret_cast<const float4*>(Ue + ss * NT + t4);
        UeTc[t4 + 0][sg] = u4.x;
        UeTc[t4 + 1][sg] = u4.y;
        UeTc[t4 + 2][sg] = u4.z;
        UeTc[t4 + 3][sg] = u4.w;
      }
      __syncthreads();
#pragma unroll 4
      for (int t = 0; t < NT; ++t) {
        const float4 xv = *reinterpret_cast<const float4*>(&xh[t][4 * dq]);
        const float u = UeTc[t][sg];
        acc[4*c+0] = fmaf(xv.x, u, acc[4*c+0]);
        acc[4*c+1] = fmaf(xv.y, u, acc[4*c+1]);
        acc[4*c+2] = fmaf(xv.z, u, acc[4*c+2]);
        acc[4*c+3] = fmaf(xv.w, u, acc[4*c+3]);
      }
      __syncthreads();
    }
#pragma unroll
    for (int c = 0; c < 4; ++c) {
      const int ss = sg + 32 * c;
      const float ub = Ueb[ss];
#pragma unroll
      for (int di = 0; di < 4; ++di) {
        const float e = fexp2(C2 * (acc[4*c+di] + ub));
        Ebt[4*dq + di][ss] = f2bf(e);
      }
    }
  }
  __syncthreads();   // Ebt complete before register loads

  // zero h/c state (both parities)
  if (tid < 192) (&hcpk[0][0][0])[tid] = 0u;          // half2(0,0)
  if (tid < 192) (&cq[0][0][0])[tid] = 0.f;

  // ---------------- persistent per-thread registers -------------------------
  // phase A: 8 threads per s; C2 folded into weights/bias -> exp2 arg direct
  const int s_a = tid >> 3, r_a = tid & 7;
  unsigned wehs_p[8];
#pragma unroll
  for (int i = 0; i < 4; ++i) {
    const float4 v4 = *reinterpret_cast<const float4*>(Wehs + s_a * 128 + r_a * 16 + 4 * i);
    wehs_p[2*i]   = pkf16(C2 * v4.x, C2 * v4.y);
    wehs_p[2*i+1] = pkf16(C2 * v4.z, C2 * v4.w);
  }
  float behs_r = C2 * behs[s_a];

  // phase B: lane = s_l + 16*dp; d0 = 8*wid + 2*dp; L2E folded into mv
  const int s_l = lane & 15;
  const int dp  = lane >> 4;
  const int d0  = 8 * wid + 2 * dp;
  f32x2 mv[4];
  {
    const float4 va = *reinterpret_cast<const float4*>(vew + 8 * s_l);
    const float4 vb = *reinterpret_cast<const float4*>(vew + 8 * s_l + 4);
    const float k = -2.f * L2E;
    mv[0] = (f32x2){k * va.x, k * va.y};
    mv[1] = (f32x2){k * va.z, k * va.w};
    mv[2] = (f32x2){k * vb.x, k * vb.y};
    mv[3] = (f32x2){k * vb.z, k * vb.w};
  }
  // E fragments as f32 pairs (time-invariant, pre-unpacked from bf16)
  f32x2 er2[8];
  {
    const int4 ea = *reinterpret_cast<const int4*>(&Ebt[d0][8 * s_l]);
    const int4 eb = *reinterpret_cast<const int4*>(&Ebt[d0 + 1][8 * s_l]);
    er2[0] = (f32x2){blo((unsigned)ea.x), bhi((unsigned)ea.x)};
    er2[1] = (f32x2){blo((unsigned)ea.y), bhi((unsigned)ea.y)};
    er2[2] = (f32x2){blo((unsigned)ea.z), bhi((unsigned)ea.z)};
    er2[3] = (f32x2){blo((unsigned)ea.w), bhi((unsigned)ea.w)};
    er2[4] = (f32x2){blo((unsigned)eb.x), bhi((unsigned)eb.x)};
    er2[5] = (f32x2){blo((unsigned)eb.y), bhi((unsigned)eb.y)};
    er2[6] = (f32x2){blo((unsigned)eb.z), bhi((unsigned)eb.z)};
    er2[7] = (f32x2){blo((unsigned)eb.w), bhi((unsigned)eb.w)};
  }

  // phase D+E: lane = 16*kk + cD; unit kD = 4*wid + kk; 4 gates per lane
  const int kk = lane >> 4, cD = lane & 15;
  const int kD = 4 * wid + kk;
  unsigned wx2[16], wh2[8];   // half2-packed gate weights
  float b4[4];
#pragma unroll
  for (int g = 0; g < 4; ++g) {
    const int j = 64 * g + kD;
    const float4 u0 = *reinterpret_cast<const float4*>(Wih + j * 128 + 8 * cD);
    const float4 u1 = *reinterpret_cast<const float4*>(Wih + j * 128 + 8 * cD + 4);
    wx2[4*g]   = pkf16(u0.x, u0.y);
    wx2[4*g+1] = pkf16(u0.z, u0.w);
    wx2[4*g+2] = pkf16(u1.x, u1.y);
    wx2[4*g+3] = pkf16(u1.z, u1.w);
    const float4 u2 = *reinterpret_cast<const float4*>(Whh + j * 64 + 4 * cD);
    wh2[2*g]   = pkf16(u2.x, u2.y);
    wh2[2*g+1] = pkf16(u2.z, u2.w);
    b4[g] = bih[j] + bhh[j];
  }

#pragma unroll
  for (int i = 0; i < 8; ++i) PIN(wehs_p[i]);
#pragma unroll
  for (int i = 0; i < 8; ++i) PIN(er2[i]);
#pragma unroll
  for (int i = 0; i < 4; ++i) PIN(mv[i]);
#pragma unroll
  for (int i = 0; i < 16; ++i) PIN(wx2[i]);
#pragma unroll
  for (int i = 0; i < 8; ++i) PIN(wh2[i]);
#pragma unroll
  for (int g = 0; g < 4; ++g) PIN(b4[g]);
  PIN(behs_r);

  __syncthreads();

  // ---------------- main recurrence: unrolled x2, compile-time parity -------
#define STEP(T, P) do {                                                        \
    const float2 xv = *reinterpret_cast<const float2*>(&xh[(T)][d0]);          \
    /* A: w[s] = exp2(C2*(h.W+b)) — C2 prefolded */ {                          \
      const int4 q0 = *reinterpret_cast<const int4*>(&hcpk[(P)][r_a][0]);      \
      const int4 q1 = *reinterpret_cast<const int4*>(&hcpk[(P)][r_a][4]);      \
      float a0 = 0.f, a1 = 0.f;                                                \
      a0 = dot2((unsigned)q0.x, wehs_p[0], a0);                                \
      a1 = dot2((unsigned)q0.y, wehs_p[1], a1);                                \
      a0 = dot2((unsigned)q0.z, wehs_p[2], a0);                                \
      a1 = dot2((unsigned)q0.w, wehs_p[3], a1);                                \
      a0 = dot2((unsigned)q1.x, wehs_p[4], a0);                                \
      a1 = dot2((unsigned)q1.y, wehs_p[5], a1);                                \
      a0 = dot2((unsigned)q1.z, wehs_p[6], a0);                                \
      a1 = dot2((unsigned)q1.w, wehs_p[7], a1);                                \
      float a = a0 + a1;                                                       \
      a = dppadd<0xB1>(a);                                                     \
      a = dppadd<0x4E>(a);                                                     \
      a = dppadd<0x141>(a);                                                    \
      if (r_a == 0) wvm[s_a >> 3][s_a & 7] = fexp2(a + behs_r);                \
    }                                                                          \
    __syncthreads();                                                           \
    int2 hh; float c_old;                                                      \
    /* B: e[d] = exp2(L2E*v) — L2E prefolded into mv */ {                      \
      const float4 wa = *reinterpret_cast<const float4*>(&wvm[s_l][0]);        \
      const float4 wb = *reinterpret_cast<const float4*>(&wvm[s_l][4]);        \
      hh    = *reinterpret_cast<const int2*>(&hcpk[(P)][cD >> 2][2 * (cD & 3)]); \
      c_old = cq[(P)][wid][kk];                                                \
      const f32x2 one2 = {1.f, 1.f};                                           \
      const f32x2 w01 = {wa.x, wa.y}, w23 = {wa.z, wa.w};                      \
      const f32x2 w45 = {wb.x, wb.y}, w67 = {wb.z, wb.w};                      \
      f32x2 ac0 = {0.f, 0.f}, ac0b = {0.f, 0.f};                               \
      f32x2 ac1 = {0.f, 0.f}, ac1b = {0.f, 0.f};                               \
      BSTEP(w01, er2[0], mv[0], ac0);                                          \
      BSTEP(w23, er2[1], mv[1], ac0b);                                         \
      BSTEP(w45, er2[2], mv[2], ac0);                                          \
      BSTEP(w67, er2[3], mv[3], ac0b);                                         \
      BSTEP(w01, er2[4], mv[0], ac1);                                          \
      BSTEP(w23, er2[5], mv[1], ac1b);                                         \
      BSTEP(w45, er2[6], mv[2], ac1);                                          \
      BSTEP(w67, er2[7], mv[3], ac1b);                                         \
      const f32x2 sv0 = ac0 + ac0b;                                            \
      const f32x2 sv1 = ac1 + ac1b;                                            \
      float s0 = sum16(sv0.x + sv0.y);                                         \
      float s1 = sum16(sv1.x + sv1.y);                                         \
      const float e0 = fexp2(s0);                                              \
      const float e1 = fexp2(s1);                                              \
      if (s_l == 0) {                                                          \
        part64[4 * wid + dp] = e0 + e1;                                        \
        xpk[wid][dp] = pkf16(e0 * xv.x, e1 * xv.y);                            \
        *reinterpret_cast<float2*>(&xh[(T)][d0]) =                             \
            make_float2(e0 * xv.x, e1 * xv.y);                                 \
      }                                                                        \
    }                                                                          \
    __syncthreads();                                                           \
    /* D+E: gate dot2 first (no rs dependency), Σe reduce in parallel */ {     \
      const int4 xq = *reinterpret_cast<const int4*>(&xpk[cD][0]);             \
      float sx[4], sh[4];                                                      \
      _Pragma("unroll")                                                        \
      for (int g = 0; g < 4; ++g) {                                            \
        float s = 0.f;                                                         \
        s = dot2((unsigned)xq.x, wx2[4*g],   s);                               \
        s = dot2((unsigned)xq.y, wx2[4*g+1], s);                               \
        s = dot2((unsigned)xq.z, wx2[4*g+2], s);                               \
        s = dot2((unsigned)xq.w, wx2[4*g+3], s);                               \
        sx[g] = s;                                                             \
        float h = 0.f;                                                         \
        h = dot2((unsigned)hh.x, wh2[2*g],   h);                               \
        h = dot2((unsigned)hh.y, wh2[2*g+1], h);                               \
        sh[g] = h;                                                             \
      }                                                                        \
      float tot = part64[lane];                                                \
      tot = sum16(tot);                                                        \
      tot += __int_as_float(__builtin_amdgcn_ds_swizzle(__float_as_int(tot), 0x401F)); \
      tot += __shfl_xor(tot, 32);                                              \
      const float rs = frcp(tot);                                              \
      float ac[4];                                                             \
      _Pragma("unroll")                                                        \
      for (int g = 0; g < 4; ++g) ac[g] = sum16(fmaf(sx[g], rs, sh[g]));       \
      const float gi = ac[0] + b4[0];                                          \
      const float gf = ac[1] + b4[1];                                          \
      const float gG = ac[2] + b4[2];                                          \
      const float go = ac[3] + b4[3];                                          \
      const float si = frcp(1.f + fexp2(-L2E * gi));                           \
      const float sf = frcp(1.f + fexp2(-L2E * gf));                           \
      const float tg = 1.f - 2.f * frcp(1.f + fexp2(C2 * gG));                 \
      const float cn = fmaf(sf, c_old, si * tg);                               \
      const float so = frcp(1.f + fexp2(-L2E * go));                           \
      const float tc = 1.f - 2.f * frcp(1.f + fexp2(C2 * cn));                 \
      const float hn = so * tc;                                                \
      if (cD == 0) {                                                           \
        __half* Hb = reinterpret_cast<__half*>(&hcpk[(P) ^ 1][0][0]);          \
        Hb[(kD >> 4) * 24 + (kD & 15)]       = __float2half_rn(hn);            \
        Hb[(4 + (kD >> 4)) * 24 + (kD & 15)] = __float2half_rn(cn);            \
        cq[(P) ^ 1][wid][kk] = cn;                                             \
        hbuf[(T)][kD] = hn;                                                    \
      }                                                                        \
      if (tid == 0) rsb[(T)] = rs;                                             \
    }                                                                          \
    __syncthreads();                                                           \
  } while (0)

#define BSTEP(W, E, M, ACC) do {                                   \
    f32x2 q_ = __builtin_elementwise_fma(W, E, one2);              \
    f32x2 r_; r_.x = frcp(q_.x); r_.y = frcp(q_.y);                \
    ACC = __builtin_elementwise_fma(M, r_, ACC);                   \
  } while (0)

  for (int t = 0; t < NT; t += 2) {
    STEP(t, 0);
    STEP(t + 1, 1);
  }
#undef BSTEP
#undef STEP

  // ---------------- bulk flush of outputs -----------------------------------
#pragma unroll
  for (int i = 0; i < 4; ++i) {
    const int f = i * 1024 + tid;
    const int t = f >> 5, c = (f & 31) << 2;
    float4 v = *reinterpret_cast<const float4*>(&xh[t][c]);
    const float rs = rsb[t];
    v.x *= rs; v.y *= rs; v.z *= rs; v.w *= rs;
    *reinterpret_cast<float4*>(out + b * (NT * ND) + t * ND + c) = v;
  }
  float* out2 = out + NB * (NT * ND) + b * (NT * NH);
#pragma unroll
  for (int i = 0; i < 2; ++i) {
    const int f = i * 1024 + tid;
    const int t = f >> 4, c = (f & 15) << 2;
    *reinterpret_cast<float4*>(out2 + t * NH + c) =
        *reinterpret_cast<const float4*>(&hbuf[t][c]);
  }
}

extern "C" void kernel_launch(void* const* d_in, const int* in_sizes, int n_in,
                              void* d_out, int out_size, void* d_ws, size_t ws_size,
                              hipStream_t stream) {
  const float* x    = (const float*)d_in[0];
  const float* Wehs = (const float*)d_in[1];
  const float* behs = (const float*)d_in[2];
  const float* Ue   = (const float*)d_in[3];
  const float* Ueb  = (const float*)d_in[4];
  const float* vew  = (const float*)d_in[5];
  // d_in[6] = v_e_b: constant shift before softmax -> no effect, unused.
  const float* Wih  = (const float*)d_in[7];
  const float* Whh  = (const float*)d_in[8];
  const float* bih  = (const float*)d_in[9];
  const float* bhh  = (const float*)d_in[10];
  float* out = (float*)d_out;

  darnn_enc<<<NB, NTH, 0, stream>>>(x, Wehs, behs, Ue, Ueb, vew, Wih, Whh, bih, bhh, out);
}